// Round 8
// baseline (226.966 us; speedup 1.0000x reference)
//
#include <hip/hip_runtime.h>
#include <math.h>

#define PI_F 3.14159265358979323846f

typedef unsigned int u32x2 __attribute__((ext_vector_type(2)));

// One wave = one batch element's 10-qubit statevector.
// Amp index bits[9:4]=lane, bits[3:0]=reg. Wire w <-> bit (9-w).
// Cross-lane wires: w0 xor32 -> v_permlane32_swap (VALU builtin), w1 xor16 ->
// v_permlane16_swap (VALU builtin), w2 xor8 -> DPP row_ror:8, w3 xor4 ->
// ds_swizzle (only DS shuffle), w4/w5 xor2/1 -> DPP quad_perm.
// Wires 6..9 in-register. Scalar f32 math (v_pk_* NOT dual-rate on CDNA4, R6).
// CNOT cascade lane-part = Gray-code ds_bpermute. H raw; 2^-20 in epilogue.
// R7 lesson: raw inline-asm permlane lacks backend hazard s_nops -> corrupt.
// Use builtins (compiler inserts wait states); __has_builtin fallback to R6.

template <int CTRL>
__device__ __forceinline__ float dppf(float v) {
  return __int_as_float(__builtin_amdgcn_update_dpp(
      __float_as_int(v), __float_as_int(v), CTRL, 0xF, 0xF, false));
}

#if __has_builtin(__builtin_amdgcn_permlane32_swap)
// swap(v,v): r.x = [lo,lo], r.y = [hi,hi]  (32-lane halves)
__device__ __forceinline__ float pswap32(float v, int lane) {
  u32x2 r = __builtin_amdgcn_permlane32_swap(__float_as_uint(v),
                                             __float_as_uint(v), false, false);
  return __uint_as_float((lane & 32) ? r.x : r.y);
}
__device__ __forceinline__ float psum32(float v) {
  u32x2 r = __builtin_amdgcn_permlane32_swap(__float_as_uint(v),
                                             __float_as_uint(v), false, false);
  return __uint_as_float(r.x) + __uint_as_float(r.y);
}
#else
__device__ __forceinline__ float pswap32(float v, int lane) {
  (void)lane;
  return __shfl_xor(v, 32, 64);
}
__device__ __forceinline__ float psum32(float v) { return v + __shfl_xor(v, 32, 64); }
#endif

#if __has_builtin(__builtin_amdgcn_permlane16_swap)
// swap(v,v): r.x = [r0,r0,r2,r2], r.y = [r1,r1,r3,r3]  (16-lane rows)
__device__ __forceinline__ float pswap16(float v, int lane) {
  u32x2 r = __builtin_amdgcn_permlane16_swap(__float_as_uint(v),
                                             __float_as_uint(v), false, false);
  return __uint_as_float((lane & 16) ? r.x : r.y);
}
__device__ __forceinline__ float psum16(float v) {
  u32x2 r = __builtin_amdgcn_permlane16_swap(__float_as_uint(v),
                                             __float_as_uint(v), false, false);
  return __uint_as_float(r.x) + __uint_as_float(r.y);
}
#else
__device__ __forceinline__ float pswap16(float v, int lane) {
  (void)lane;
  return __int_as_float(
      __builtin_amdgcn_ds_swizzle(__float_as_int(v), (16 << 10) | 0x1f));
}
__device__ __forceinline__ float psum16(float v) { return v + pswap16(v, 0); }
#endif

template <int M>
__device__ __forceinline__ float shx(float v, int lane) {
  if constexpr (M == 1) {
    return dppf<0xB1>(v);                     // quad_perm [1,0,3,2]
  } else if constexpr (M == 2) {
    return dppf<0x4E>(v);                     // quad_perm [2,3,0,1]
  } else if constexpr (M == 4) {
    return __int_as_float(
        __builtin_amdgcn_ds_swizzle(__float_as_int(v), (4 << 10) | 0x1f));
  } else if constexpr (M == 8) {
    return dppf<0x128>(v);                    // row_ror:8 == xor 8
  } else if constexpr (M == 16) {
    return pswap16(v, lane);
  } else {
    return pswap32(v, lane);
  }
}

__device__ __forceinline__ float bfly_sum(float v, int lane) {
  v += shx<1>(v, lane);
  v += shx<2>(v, lane);
  v += shx<4>(v, lane);
  v += shx<8>(v, lane);
  v = psum16(v);
  v = psum32(v);
  return v;
}

__device__ __forceinline__ float ftanh(float x) {
  float e = __expf(2.0f * x);
  return 1.0f - 2.0f / (e + 1.0f);
}

// RAW Hadamard (no 1/sqrt2)
template <int W>
__device__ __forceinline__ void apply_h(float (&sr)[16], float (&si)[16], int lane) {
  if constexpr (W <= 5) {
    constexpr int lb = 5 - W;
    const float g = ((lane >> lb) & 1) ? -1.0f : 1.0f;
#pragma unroll
    for (int r = 0; r < 16; ++r) {
      float pr = shx<(1 << lb)>(sr[r], lane);
      float pi = shx<(1 << lb)>(si[r], lane);
      sr[r] = fmaf(g, sr[r], pr);
      si[r] = fmaf(g, si[r], pi);
    }
  } else {
    constexpr int rb = 9 - W;
#pragma unroll
    for (int r = 0; r < 16; ++r) {
      if ((r >> rb) & 1) continue;
      const int r1 = r | (1 << rb);
      float a0r = sr[r], a1r = sr[r1], a0i = si[r], a1i = si[r1];
      sr[r]  = a0r + a1r;  si[r]  = a0i + a1i;
      sr[r1] = a0r - a1r;  si[r1] = a0i - a1i;
    }
  }
}

template <int W>
__device__ __forceinline__ void apply_ry(float (&sr)[16], float (&si)[16], int lane,
                                         float c, float s) {
  if constexpr (W <= 5) {
    constexpr int lb = 5 - W;
    const float t = ((lane >> lb) & 1) ? s : -s;
#pragma unroll
    for (int r = 0; r < 16; ++r) {
      float qr = c * sr[r];
      float qi = c * si[r];
      float pr = shx<(1 << lb)>(sr[r], lane);
      float pi = shx<(1 << lb)>(si[r], lane);
      sr[r] = fmaf(t, pr, qr);
      si[r] = fmaf(t, pi, qi);
    }
  } else {
    constexpr int rb = 9 - W;
#pragma unroll
    for (int r = 0; r < 16; ++r) {
      if ((r >> rb) & 1) continue;
      const int r1 = r | (1 << rb);
      float a0r = sr[r], a1r = sr[r1], a0i = si[r], a1i = si[r1];
      sr[r]  = fmaf(-s, a1r, c * a0r);  si[r]  = fmaf(-s, a1i, c * a0i);
      sr[r1] = fmaf( s, a0r, c * a1r);  si[r1] = fmaf( s, a0i, c * a1i);
    }
  }
}

// CNOT(control=C, target=C+1), reg-side tail of the cascade
template <int C>
__device__ __forceinline__ void apply_cnot(float (&sr)[16], float (&si)[16], int lane) {
  if constexpr (C == 5) {                     // control lane bit 0, target reg bit 3
    const bool ctrl = lane & 1;
#pragma unroll
    for (int r = 0; r < 8; ++r) {
      float t0r = sr[r], t1r = sr[r + 8];
      float t0i = si[r], t1i = si[r + 8];
      sr[r] = ctrl ? t1r : t0r;  sr[r + 8] = ctrl ? t0r : t1r;
      si[r] = ctrl ? t1i : t0i;  si[r + 8] = ctrl ? t0i : t1i;
    }
  } else {                                    // both reg bits: pure SSA renaming
    constexpr int cb = 9 - C;
    constexpr int tb = 8 - C;
#pragma unroll
    for (int r = 0; r < 16; ++r) {
      if (!(((r >> cb) & 1) && !((r >> tb) & 1))) continue;
      const int r1 = r | (1 << tb);
      float tr = sr[r]; sr[r] = sr[r1]; sr[r1] = tr;
      float ti = si[r]; si[r] = si[r1]; si[r1] = ti;
    }
  }
}

// Full CNOT cascade C(0,1)..C(8,9): lane-wire part is the Gray permutation.
__device__ __forceinline__ void cascade(float (&sr)[16], float (&si)[16], int lane) {
  const int addr = ((lane ^ (lane >> 1)) << 2);
#pragma unroll
  for (int r = 0; r < 16; ++r) {
    sr[r] = __int_as_float(__builtin_amdgcn_ds_bpermute(addr, __float_as_int(sr[r])));
    si[r] = __int_as_float(__builtin_amdgcn_ds_bpermute(addr, __float_as_int(si[r])));
  }
  apply_cnot<5>(sr, si, lane);
  apply_cnot<6>(sr, si, lane);
  apply_cnot<7>(sr, si, lane);
  apply_cnot<8>(sr, si, lane);
}

// Batch-uniform RA-layer trig table: tab[0..59] = cos(qp*0.5), tab[60..119] = sin.
__global__ void dqc_trig_kernel(const float* __restrict__ qp, float* __restrict__ tab) {
  int t = threadIdx.x;
  if (t < 60) {
    float th = qp[t] * 0.5f;
    tab[t]      = __cosf(th);
    tab[60 + t] = __sinf(th);
  }
}

__global__ __launch_bounds__(256) void dqc_kernel(
    const float* __restrict__ x, const float* __restrict__ pre_w,
    const float* __restrict__ pre_b, const float* __restrict__ q_params,
    const float* __restrict__ post_w, const float* __restrict__ post_b,
    const float* __restrict__ tab, float* __restrict__ out) {
  const int lane = threadIdx.x & 63;
  const int wave = threadIdx.x >> 6;
  const int b = blockIdx.x * 4 + wave;

  // ---------- pre layer: q_in[w] = tanh(x[b] . pre_w[w] + pre_b[w]) * pi/2
  const float* xb = x + (size_t)b * 512 + lane * 8;
  const float4 xv0 = *(const float4*)(xb);
  const float4 xv1 = *(const float4*)(xb + 4);
  float qin[10];
#pragma unroll
  for (int q = 0; q < 10; ++q) {
    const float* wp = pre_w + q * 512 + lane * 8;
    const float4 w0 = *(const float4*)(wp);
    const float4 w1 = *(const float4*)(wp + 4);
    float a = xv0.x * w0.x + xv0.y * w0.y + xv0.z * w0.z + xv0.w * w0.w +
              xv1.x * w1.x + xv1.y * w1.y + xv1.z * w1.z + xv1.w * w1.w;
    a = bfly_sum(a, lane);
    qin[q] = ftanh(a + pre_b[q]) * (PI_F * 0.5f);
  }

  // angle constants (all wave-uniform)
  float tq[10], phi[9];
#pragma unroll
  for (int w = 0; w < 10; ++w) tq[w] = 2.0f * qin[w];
#pragma unroll
  for (int i = 0; i < 9; ++i)
    phi[i] = 2.0f * (PI_F - qin[i]) * (PI_F - qin[i + 1]);

  float sr[16], si[16];

  // ---------- ZZFM rep 1 (analytic): amp(y) = e^{i*theta1(y)}
  {
    float A1 = 0.0f;
    int bprev = 0;
#pragma unroll
    for (int w = 0; w <= 5; ++w) {
      int bw = (lane >> (5 - w)) & 1;
      A1 += (bw ^ bprev) ? tq[w] : 0.0f;
      bprev = bw;
    }
#pragma unroll
    for (int i = 0; i <= 4; ++i)
      A1 += ((lane >> (5 - (i + 1))) & 1) ? phi[i] : 0.0f;
    const int b5 = lane & 1;
    const float m0 = A1 + (b5 ? tq[6] : 0.0f);   // regs with bit6 = 0
    const float m1 = A1 + (b5 ? 0.0f : tq[6]);   // regs with bit6 = 1
#pragma unroll
    for (int r = 0; r < 16; ++r) {
      const int c6 = (r >> 3) & 1, c7 = (r >> 2) & 1, c8 = (r >> 1) & 1, c9 = r & 1;
      float S = ((c6 ^ c7) ? tq[7] : 0.0f) + ((c7 ^ c8) ? tq[8] : 0.0f) +
                ((c8 ^ c9) ? tq[9] : 0.0f) +
                (c6 ? phi[5] : 0.0f) + (c7 ? phi[6] : 0.0f) +
                (c8 ? phi[7] : 0.0f) + (c9 ? phi[8] : 0.0f);
      float th = (c6 ? m1 : m0) + S;
      sr[r] = __cosf(th);
      si[r] = __sinf(th);
    }
  }

  // ---------- ZZFM rep 2: H layer (raw), folded diagonal, cascade
  apply_h<0>(sr, si, lane); apply_h<6>(sr, si, lane);
  apply_h<1>(sr, si, lane); apply_h<7>(sr, si, lane);
  apply_h<3>(sr, si, lane); apply_h<8>(sr, si, lane);
  apply_h<2>(sr, si, lane); apply_h<9>(sr, si, lane);
  apply_h<4>(sr, si, lane); apply_h<5>(sr, si, lane);
  {
    float A2 = 0.0f;
    int pfx = 0;
#pragma unroll
    for (int w = 0; w <= 5; ++w) {
      int bw = (lane >> (5 - w)) & 1;
      A2 += bw ? tq[w] : 0.0f;
      pfx ^= bw;
      if (w >= 1) A2 += pfx ? phi[w - 1] : 0.0f;   // phi_{w-1} * p_w
    }
    const bool Lb = pfx;                           // lane parity
#pragma unroll
    for (int r = 0; r < 16; ++r) {
      const int c6 = (r >> 3) & 1, c7 = (r >> 2) & 1, c8 = (r >> 1) & 1, c9 = r & 1;
      const int q6 = c6, q7 = q6 ^ c7, q8 = q7 ^ c8, q9 = q8 ^ c9;
      float S2 = (c6 ? tq[6] : 0.0f) + (c7 ? tq[7] : 0.0f) +
                 (c8 ? tq[8] : 0.0f) + (c9 ? tq[9] : 0.0f);
      float Vv = (q6 ? phi[5] : 0.0f) + (q7 ? phi[6] : 0.0f) +
                 (q8 ? phi[7] : 0.0f) + (q9 ? phi[8] : 0.0f);
      float U = (q6 ? 0.0f : phi[5]) + (q7 ? 0.0f : phi[6]) +
                (q8 ? 0.0f : phi[7]) + (q9 ? 0.0f : phi[8]);
      float th = A2 + (Lb ? (S2 + U) : (S2 + Vv));
      float c = __cosf(th), s = __sinf(th);
      float re = sr[r], im = si[r];
      sr[r] = re * c - im * s;
      si[r] = re * s + im * c;
    }
  }
  cascade(sr, si, lane);

  // ---------- RealAmplitudes: 6 x (RY layer + CNOT cascade)
#pragma unroll 1
  for (int l = 0; l < 6; ++l) {
    float qc[10], qs[10];
    if (tab) {
#pragma unroll
      for (int w = 0; w < 10; ++w) {
        qc[w] = tab[l * 10 + w];
        qs[w] = tab[60 + l * 10 + w];
      }
    } else {
#pragma unroll
      for (int w = 0; w < 10; ++w) {
        float th = q_params[l * 10 + w] * 0.5f;
        qc[w] = __cosf(th);
        qs[w] = __sinf(th);
      }
    }
#define RYW(W) apply_ry<W>(sr, si, lane, qc[W], qs[W]);
    RYW(0) RYW(6) RYW(1) RYW(7) RYW(3) RYW(8) RYW(2) RYW(9) RYW(4) RYW(5)
#undef RYW
    cascade(sr, si, lane);
  }

  // ---------- epilogue: out = (sum_r p_r * (G(lane) + K[r])) reduced, * 2^-20
  const float SC = 1.0f / 1048576.0f;
  const float pw06 = post_w[6], pw07 = post_w[7], pw08 = post_w[8], pw09 = post_w[9];
  const float pw16 = post_w[16], pw17 = post_w[17], pw18 = post_w[18], pw19 = post_w[19];
  float k89a[4], k89b[4];
  {
    float a0 = pw08 + pw09, a1 = pw08 - pw09;
    k89a[0] = a0; k89a[1] = a1; k89a[2] = -a1; k89a[3] = -a0;
    float b0 = pw18 + pw19, b1 = pw18 - pw19;
    k89b[0] = b0; k89b[1] = b1; k89b[2] = -b1; k89b[3] = -b0;
  }
  float G0 = 0.0f, G1 = 0.0f;
#pragma unroll
  for (int w = 0; w < 6; ++w) {
    const bool n = (lane >> (5 - w)) & 1;
    const float pa = post_w[w], pb = post_w[10 + w];
    G0 += n ? -pa : pa;
    G1 += n ? -pb : pb;
  }
  float o0 = 0.0f, o1 = 0.0f;
#pragma unroll
  for (int r = 0; r < 16; ++r) {
    const float K0 = ((r & 8) ? -pw06 : pw06) + ((r & 4) ? -pw07 : pw07) + k89a[r & 3];
    const float K1 = ((r & 8) ? -pw16 : pw16) + ((r & 4) ? -pw17 : pw17) + k89b[r & 3];
    float p = sr[r] * sr[r] + si[r] * si[r];
    o0 = fmaf(p, G0 + K0, o0);
    o1 = fmaf(p, G1 + K1, o1);
  }
  o0 = bfly_sum(o0, lane);
  o1 = bfly_sum(o1, lane);

  if (lane == 0) {
    *(float2*)(out + (size_t)b * 2) =
        make_float2(o0 * SC + post_b[0], o1 * SC + post_b[1]);
  }
}

extern "C" void kernel_launch(void* const* d_in, const int* in_sizes, int n_in,
                              void* d_out, int out_size, void* d_ws, size_t ws_size,
                              hipStream_t stream) {
  (void)n_in; (void)out_size;
  const float* x      = (const float*)d_in[0];
  const float* pre_w  = (const float*)d_in[1];
  const float* pre_b  = (const float*)d_in[2];
  const float* qp     = (const float*)d_in[3];
  const float* post_w = (const float*)d_in[4];
  const float* post_b = (const float*)d_in[5];
  float* out = (float*)d_out;

  float* tab = nullptr;
  if (ws_size >= 120 * sizeof(float)) {
    tab = (float*)d_ws;
    hipLaunchKernelGGL(dqc_trig_kernel, dim3(1), dim3(64), 0, stream, qp, tab);
  }

  const int batch = in_sizes[0] / 512;  // 16384
  dim3 grid(batch / 4), block(256);
  hipLaunchKernelGGL(dqc_kernel, grid, block, 0, stream,
                     x, pre_w, pre_b, qp, post_w, post_b, tab, out);
}

// Round 9
// 172.536 us; speedup vs baseline: 1.3155x; 1.3155x over previous
//
#include <hip/hip_runtime.h>
#include <math.h>

#define PI_F 3.14159265358979323846f

// One wave = one batch element's 10-qubit statevector.
// Amp index bits[9:4]=lane, bits[3:0]=reg. Wire w <-> bit (9-w).
// Cross-lane wires: w4/w5 xor2/1 -> DPP quad_perm, w2 xor8 -> DPP row_ror:8,
// w3 xor4 / w1 xor16 -> ds_swizzle, w0 xor32 -> shfl. Wires 6..9 in-register.
// SCALAR f32 math: R6 proved v_pk_* costs MORE than 2 scalar ops on CDNA4
// (11.5K vs 8.2K VALU instr/wave); R8 proved permlane_swap builtins cost ~4x
// (17.6K). Scalar fmaf + DPP placement is the measured-lean combination.
// CNOT cascade lane-part = Gray-code ds_bpermute. H raw; 2^-20 in epilogue.

template <int CTRL>
__device__ __forceinline__ float dppf(float v) {
  return __int_as_float(__builtin_amdgcn_update_dpp(
      __float_as_int(v), __float_as_int(v), CTRL, 0xF, 0xF, false));
}

template <int M>
__device__ __forceinline__ float shx(float v) {
  if constexpr (M == 1) {
    return dppf<0xB1>(v);                     // quad_perm [1,0,3,2]
  } else if constexpr (M == 2) {
    return dppf<0x4E>(v);                     // quad_perm [2,3,0,1]
  } else if constexpr (M == 8) {
    return dppf<0x128>(v);                    // row_ror:8 == xor 8 (R6-proven)
  } else if constexpr (M < 32) {              // 4, 16
    return __int_as_float(
        __builtin_amdgcn_ds_swizzle(__float_as_int(v), (M << 10) | 0x1f));
  } else {
    return __shfl_xor(v, 32, 64);
  }
}

__device__ __forceinline__ float bfly_sum(float v) {
  v += shx<1>(v); v += shx<2>(v); v += shx<4>(v);
  v += shx<8>(v); v += shx<16>(v); v += shx<32>(v);
  return v;
}

__device__ __forceinline__ float ftanh(float x) {
  float e = __expf(2.0f * x);
  return 1.0f - 2.0f / (e + 1.0f);
}

// RAW Hadamard (no 1/sqrt2)
template <int W>
__device__ __forceinline__ void apply_h(float (&sr)[16], float (&si)[16], int lane) {
  if constexpr (W <= 5) {
    constexpr int lb = 5 - W;
    const float g = ((lane >> lb) & 1) ? -1.0f : 1.0f;
#pragma unroll
    for (int r = 0; r < 16; ++r) {
      float pr = shx<(1 << lb)>(sr[r]);
      float pi = shx<(1 << lb)>(si[r]);
      sr[r] = fmaf(g, sr[r], pr);
      si[r] = fmaf(g, si[r], pi);
    }
  } else {
    constexpr int rb = 9 - W;
#pragma unroll
    for (int r = 0; r < 16; ++r) {
      if ((r >> rb) & 1) continue;
      const int r1 = r | (1 << rb);
      float a0r = sr[r], a1r = sr[r1], a0i = si[r], a1i = si[r1];
      sr[r]  = a0r + a1r;  si[r]  = a0i + a1i;
      sr[r1] = a0r - a1r;  si[r1] = a0i - a1i;
    }
  }
}

template <int W>
__device__ __forceinline__ void apply_ry(float (&sr)[16], float (&si)[16], int lane,
                                         float c, float s) {
  if constexpr (W <= 5) {
    constexpr int lb = 5 - W;
    const float t = ((lane >> lb) & 1) ? s : -s;
#pragma unroll
    for (int r = 0; r < 16; ++r) {
      float qr = c * sr[r];
      float qi = c * si[r];
      float pr = shx<(1 << lb)>(sr[r]);
      float pi = shx<(1 << lb)>(si[r]);
      sr[r] = fmaf(t, pr, qr);
      si[r] = fmaf(t, pi, qi);
    }
  } else {
    constexpr int rb = 9 - W;
#pragma unroll
    for (int r = 0; r < 16; ++r) {
      if ((r >> rb) & 1) continue;
      const int r1 = r | (1 << rb);
      float a0r = sr[r], a1r = sr[r1], a0i = si[r], a1i = si[r1];
      sr[r]  = fmaf(-s, a1r, c * a0r);  si[r]  = fmaf(-s, a1i, c * a0i);
      sr[r1] = fmaf( s, a0r, c * a1r);  si[r1] = fmaf( s, a0i, c * a1i);
    }
  }
}

// CNOT(control=C, target=C+1), reg-side tail of the cascade
template <int C>
__device__ __forceinline__ void apply_cnot(float (&sr)[16], float (&si)[16], int lane) {
  if constexpr (C == 5) {                     // control lane bit 0, target reg bit 3
    const bool ctrl = lane & 1;
#pragma unroll
    for (int r = 0; r < 8; ++r) {
      float t0r = sr[r], t1r = sr[r + 8];
      float t0i = si[r], t1i = si[r + 8];
      sr[r] = ctrl ? t1r : t0r;  sr[r + 8] = ctrl ? t0r : t1r;
      si[r] = ctrl ? t1i : t0i;  si[r + 8] = ctrl ? t0i : t1i;
    }
  } else {                                    // both reg bits: pure SSA renaming
    constexpr int cb = 9 - C;
    constexpr int tb = 8 - C;
#pragma unroll
    for (int r = 0; r < 16; ++r) {
      if (!(((r >> cb) & 1) && !((r >> tb) & 1))) continue;
      const int r1 = r | (1 << tb);
      float tr = sr[r]; sr[r] = sr[r1]; sr[r1] = tr;
      float ti = si[r]; si[r] = si[r1]; si[r1] = ti;
    }
  }
}

// Full CNOT cascade C(0,1)..C(8,9): lane-wire part is the Gray permutation.
__device__ __forceinline__ void cascade(float (&sr)[16], float (&si)[16], int lane) {
  const int addr = ((lane ^ (lane >> 1)) << 2);
#pragma unroll
  for (int r = 0; r < 16; ++r) {
    sr[r] = __int_as_float(__builtin_amdgcn_ds_bpermute(addr, __float_as_int(sr[r])));
    si[r] = __int_as_float(__builtin_amdgcn_ds_bpermute(addr, __float_as_int(si[r])));
  }
  apply_cnot<5>(sr, si, lane);
  apply_cnot<6>(sr, si, lane);
  apply_cnot<7>(sr, si, lane);
  apply_cnot<8>(sr, si, lane);
}

// Batch-uniform RA-layer trig table: tab[0..59] = cos(qp*0.5), tab[60..119] = sin.
__global__ void dqc_trig_kernel(const float* __restrict__ qp, float* __restrict__ tab) {
  int t = threadIdx.x;
  if (t < 60) {
    float th = qp[t] * 0.5f;
    tab[t]      = __cosf(th);
    tab[60 + t] = __sinf(th);
  }
}

__global__ __launch_bounds__(256) void dqc_kernel(
    const float* __restrict__ x, const float* __restrict__ pre_w,
    const float* __restrict__ pre_b, const float* __restrict__ q_params,
    const float* __restrict__ post_w, const float* __restrict__ post_b,
    const float* __restrict__ tab, float* __restrict__ out) {
  const int lane = threadIdx.x & 63;
  const int wave = threadIdx.x >> 6;
  const int b = blockIdx.x * 4 + wave;

  // ---------- pre layer: q_in[w] = tanh(x[b] . pre_w[w] + pre_b[w]) * pi/2
  const float* xb = x + (size_t)b * 512 + lane * 8;
  const float4 xv0 = *(const float4*)(xb);
  const float4 xv1 = *(const float4*)(xb + 4);
  float qin[10];
#pragma unroll
  for (int q = 0; q < 10; ++q) {
    const float* wp = pre_w + q * 512 + lane * 8;
    const float4 w0 = *(const float4*)(wp);
    const float4 w1 = *(const float4*)(wp + 4);
    float a = xv0.x * w0.x + xv0.y * w0.y + xv0.z * w0.z + xv0.w * w0.w +
              xv1.x * w1.x + xv1.y * w1.y + xv1.z * w1.z + xv1.w * w1.w;
    a = bfly_sum(a);
    qin[q] = ftanh(a + pre_b[q]) * (PI_F * 0.5f);
  }

  // angle constants (all wave-uniform)
  float tq[10], phi[9];
#pragma unroll
  for (int w = 0; w < 10; ++w) tq[w] = 2.0f * qin[w];
#pragma unroll
  for (int i = 0; i < 9; ++i)
    phi[i] = 2.0f * (PI_F - qin[i]) * (PI_F - qin[i + 1]);

  float sr[16], si[16];

  // ---------- ZZFM rep 1 (analytic): amp(y) = e^{i*theta1(y)}
  {
    float A1 = 0.0f;
    int bprev = 0;
#pragma unroll
    for (int w = 0; w <= 5; ++w) {
      int bw = (lane >> (5 - w)) & 1;
      A1 += (bw ^ bprev) ? tq[w] : 0.0f;
      bprev = bw;
    }
#pragma unroll
    for (int i = 0; i <= 4; ++i)
      A1 += ((lane >> (5 - (i + 1))) & 1) ? phi[i] : 0.0f;
    const int b5 = lane & 1;
    const float m0 = A1 + (b5 ? tq[6] : 0.0f);   // regs with bit6 = 0
    const float m1 = A1 + (b5 ? 0.0f : tq[6]);   // regs with bit6 = 1
#pragma unroll
    for (int r = 0; r < 16; ++r) {
      const int c6 = (r >> 3) & 1, c7 = (r >> 2) & 1, c8 = (r >> 1) & 1, c9 = r & 1;
      float S = ((c6 ^ c7) ? tq[7] : 0.0f) + ((c7 ^ c8) ? tq[8] : 0.0f) +
                ((c8 ^ c9) ? tq[9] : 0.0f) +
                (c6 ? phi[5] : 0.0f) + (c7 ? phi[6] : 0.0f) +
                (c8 ? phi[7] : 0.0f) + (c9 ? phi[8] : 0.0f);
      float th = (c6 ? m1 : m0) + S;
      sr[r] = __cosf(th);
      si[r] = __sinf(th);
    }
  }

  // ---------- ZZFM rep 2: H layer (raw), folded diagonal, cascade
  apply_h<0>(sr, si, lane); apply_h<6>(sr, si, lane);
  apply_h<1>(sr, si, lane); apply_h<7>(sr, si, lane);
  apply_h<3>(sr, si, lane); apply_h<8>(sr, si, lane);
  apply_h<2>(sr, si, lane); apply_h<9>(sr, si, lane);
  apply_h<4>(sr, si, lane); apply_h<5>(sr, si, lane);
  {
    float A2 = 0.0f;
    int pfx = 0;
#pragma unroll
    for (int w = 0; w <= 5; ++w) {
      int bw = (lane >> (5 - w)) & 1;
      A2 += bw ? tq[w] : 0.0f;
      pfx ^= bw;
      if (w >= 1) A2 += pfx ? phi[w - 1] : 0.0f;   // phi_{w-1} * p_w
    }
    const bool Lb = pfx;                           // lane parity
#pragma unroll
    for (int r = 0; r < 16; ++r) {
      const int c6 = (r >> 3) & 1, c7 = (r >> 2) & 1, c8 = (r >> 1) & 1, c9 = r & 1;
      const int q6 = c6, q7 = q6 ^ c7, q8 = q7 ^ c8, q9 = q8 ^ c9;
      float S2 = (c6 ? tq[6] : 0.0f) + (c7 ? tq[7] : 0.0f) +
                 (c8 ? tq[8] : 0.0f) + (c9 ? tq[9] : 0.0f);
      float Vv = (q6 ? phi[5] : 0.0f) + (q7 ? phi[6] : 0.0f) +
                 (q8 ? phi[7] : 0.0f) + (q9 ? phi[8] : 0.0f);
      float U = (q6 ? 0.0f : phi[5]) + (q7 ? 0.0f : phi[6]) +
                (q8 ? 0.0f : phi[7]) + (q9 ? 0.0f : phi[8]);
      float th = A2 + (Lb ? (S2 + U) : (S2 + Vv));
      float c = __cosf(th), s = __sinf(th);
      float re = sr[r], im = si[r];
      sr[r] = re * c - im * s;
      si[r] = re * s + im * c;
    }
  }
  cascade(sr, si, lane);

  // ---------- RealAmplitudes: 6 x (RY layer + CNOT cascade)
#pragma unroll 1
  for (int l = 0; l < 6; ++l) {
    float qc[10], qs[10];
    if (tab) {
#pragma unroll
      for (int w = 0; w < 10; ++w) {
        qc[w] = tab[l * 10 + w];
        qs[w] = tab[60 + l * 10 + w];
      }
    } else {
#pragma unroll
      for (int w = 0; w < 10; ++w) {
        float th = q_params[l * 10 + w] * 0.5f;
        qc[w] = __cosf(th);
        qs[w] = __sinf(th);
      }
    }
#define RYW(W) apply_ry<W>(sr, si, lane, qc[W], qs[W]);
    RYW(0) RYW(6) RYW(1) RYW(7) RYW(3) RYW(8) RYW(2) RYW(9) RYW(4) RYW(5)
#undef RYW
    cascade(sr, si, lane);
  }

  // ---------- epilogue: out = (sum_r p_r * (G(lane) + K[r])) reduced, * 2^-20
  const float SC = 1.0f / 1048576.0f;
  const float pw06 = post_w[6], pw07 = post_w[7], pw08 = post_w[8], pw09 = post_w[9];
  const float pw16 = post_w[16], pw17 = post_w[17], pw18 = post_w[18], pw19 = post_w[19];
  float k89a[4], k89b[4];
  {
    float a0 = pw08 + pw09, a1 = pw08 - pw09;
    k89a[0] = a0; k89a[1] = a1; k89a[2] = -a1; k89a[3] = -a0;
    float b0 = pw18 + pw19, b1 = pw18 - pw19;
    k89b[0] = b0; k89b[1] = b1; k89b[2] = -b1; k89b[3] = -b0;
  }
  float G0 = 0.0f, G1 = 0.0f;
#pragma unroll
  for (int w = 0; w < 6; ++w) {
    const bool n = (lane >> (5 - w)) & 1;
    const float pa = post_w[w], pb = post_w[10 + w];
    G0 += n ? -pa : pa;
    G1 += n ? -pb : pb;
  }
  float o0 = 0.0f, o1 = 0.0f;
#pragma unroll
  for (int r = 0; r < 16; ++r) {
    const float K0 = ((r & 8) ? -pw06 : pw06) + ((r & 4) ? -pw07 : pw07) + k89a[r & 3];
    const float K1 = ((r & 8) ? -pw16 : pw16) + ((r & 4) ? -pw17 : pw17) + k89b[r & 3];
    float p = sr[r] * sr[r] + si[r] * si[r];
    o0 = fmaf(p, G0 + K0, o0);
    o1 = fmaf(p, G1 + K1, o1);
  }
  o0 = bfly_sum(o0);
  o1 = bfly_sum(o1);

  if (lane == 0) {
    *(float2*)(out + (size_t)b * 2) =
        make_float2(o0 * SC + post_b[0], o1 * SC + post_b[1]);
  }
}

extern "C" void kernel_launch(void* const* d_in, const int* in_sizes, int n_in,
                              void* d_out, int out_size, void* d_ws, size_t ws_size,
                              hipStream_t stream) {
  (void)n_in; (void)out_size;
  const float* x      = (const float*)d_in[0];
  const float* pre_w  = (const float*)d_in[1];
  const float* pre_b  = (const float*)d_in[2];
  const float* qp     = (const float*)d_in[3];
  const float* post_w = (const float*)d_in[4];
  const float* post_b = (const float*)d_in[5];
  float* out = (float*)d_out;

  float* tab = nullptr;
  if (ws_size >= 120 * sizeof(float)) {
    tab = (float*)d_ws;
    hipLaunchKernelGGL(dqc_trig_kernel, dim3(1), dim3(64), 0, stream, qp, tab);
  }

  const int batch = in_sizes[0] / 512;  // 16384
  dim3 grid(batch / 4), block(256);
  hipLaunchKernelGGL(dqc_kernel, grid, block, 0, stream,
                     x, pre_w, pre_b, qp, post_w, post_b, tab, out);
}

// Round 10
// 131.859 us; speedup vs baseline: 1.7213x; 1.3085x over previous
//
#include <hip/hip_runtime.h>
#include <math.h>

#define PI_F 3.14159265358979323846f

typedef _Float16 h2 __attribute__((ext_vector_type(2)));

// One wave = one batch element's 10-qubit statevector.
// Amp index bits[9:4]=lane, bits[3:0]=reg. Wire w <-> bit (9-w).
// Hybrid precision: pre-layer, ZZFM rep1 (analytic phases), rep2 H layer and
// folded diagonal in f32 (catastrophic-cancellation region); the 6 RA layers
// + 7 CNOT cascades run on a PACKED f16 state: V[r] = (re,im) as 2x_Float16
// in one VGPR -> v_pk_mul/fma_f16 (full-rate packed, unlike pk_f32 [R6]) and
// one 32-bit shuffle moves both components. Epilogue unpacks to f32.
// Shuffle mapping (R6/R9-proven): xor1/2 DPP quad_perm, xor8 DPP row_ror:8,
// xor4/16 ds_swizzle, xor32 shfl. Cascade lane-part = Gray ds_bpermute.
// H raw (no 1/sqrt2); 2^-20 prob scale removed in f32 epilogue.

template <int CTRL>
__device__ __forceinline__ int dppi(int v) {
  return __builtin_amdgcn_update_dpp(v, v, CTRL, 0xF, 0xF, false);
}

template <int M>
__device__ __forceinline__ int shxi(int v) {
  if constexpr (M == 1) {
    return dppi<0xB1>(v);                     // quad_perm [1,0,3,2]
  } else if constexpr (M == 2) {
    return dppi<0x4E>(v);                     // quad_perm [2,3,0,1]
  } else if constexpr (M == 8) {
    return dppi<0x128>(v);                    // row_ror:8 == xor 8
  } else if constexpr (M < 32) {              // 4, 16
    return __builtin_amdgcn_ds_swizzle(v, (M << 10) | 0x1f);
  } else {
    return __shfl_xor(v, 32, 64);
  }
}

template <int M>
__device__ __forceinline__ float shx(float v) {
  return __int_as_float(shxi<M>(__float_as_int(v)));
}

__device__ __forceinline__ float bfly_sum(float v) {
  v += shx<1>(v); v += shx<2>(v); v += shx<4>(v);
  v += shx<8>(v); v += shx<16>(v); v += shx<32>(v);
  return v;
}

__device__ __forceinline__ float ftanh(float x) {
  float e = __expf(2.0f * x);
  return 1.0f - 2.0f / (e + 1.0f);
}

__device__ __forceinline__ unsigned int h2u(h2 v) {
  return __builtin_bit_cast(unsigned int, v);
}
__device__ __forceinline__ h2 u2h(unsigned int v) {
  return __builtin_bit_cast(h2, v);
}
__device__ __forceinline__ h2 hsplat(float f) {
  _Float16 h = (_Float16)f;
  h2 r; r.x = h; r.y = h;
  return r;
}

// ---------------- f32 gates (rep2 H layer only) ----------------
template <int W>
__device__ __forceinline__ void apply_h32(float (&sr)[16], float (&si)[16], int lane) {
  if constexpr (W <= 5) {
    constexpr int lb = 5 - W;
    const float g = ((lane >> lb) & 1) ? -1.0f : 1.0f;
#pragma unroll
    for (int r = 0; r < 16; ++r) {
      float pr = shx<(1 << lb)>(sr[r]);
      float pi = shx<(1 << lb)>(si[r]);
      sr[r] = fmaf(g, sr[r], pr);
      si[r] = fmaf(g, si[r], pi);
    }
  } else {
    constexpr int rb = 9 - W;
#pragma unroll
    for (int r = 0; r < 16; ++r) {
      if ((r >> rb) & 1) continue;
      const int r1 = r | (1 << rb);
      float a0r = sr[r], a1r = sr[r1], a0i = si[r], a1i = si[r1];
      sr[r]  = a0r + a1r;  si[r]  = a0i + a1i;
      sr[r1] = a0r - a1r;  si[r1] = a0i - a1i;
    }
  }
}

// ---------------- f16 gates (RA layers + cascades) ----------------
template <int W>
__device__ __forceinline__ void apply_ry16(h2 (&V)[16], int lane,
                                           h2 cc, h2 ss, h2 ssn) {
  if constexpr (W <= 5) {
    constexpr int lb = 5 - W;
    const h2 tt = ((lane >> lb) & 1) ? ss : ssn;
#pragma unroll
    for (int r = 0; r < 16; ++r) {
      h2 P = u2h(shxi<(1 << lb)>((int)h2u(V[r])));
      V[r] = cc * V[r] + tt * P;              // v_pk_mul_f16 + v_pk_fma_f16
    }
  } else {
    constexpr int rb = 9 - W;
#pragma unroll
    for (int r = 0; r < 16; ++r) {
      if ((r >> rb) & 1) continue;
      const int r1 = r | (1 << rb);
      h2 a = V[r], b = V[r1];
      V[r]  = cc * a + ssn * b;               // c*a - s*b
      V[r1] = ss * a + cc * b;                // s*a + c*b
    }
  }
}

template <int C>
__device__ __forceinline__ void apply_cnot16(h2 (&V)[16], int lane) {
  if constexpr (C == 5) {                     // control lane bit 0, target reg bit 3
    const bool ctrl = lane & 1;
#pragma unroll
    for (int r = 0; r < 8; ++r) {
      h2 t0 = V[r], t1 = V[r + 8];
      V[r]     = ctrl ? t1 : t0;
      V[r + 8] = ctrl ? t0 : t1;
    }
  } else {                                    // both reg bits: pure SSA renaming
    constexpr int cb = 9 - C;
    constexpr int tb = 8 - C;
#pragma unroll
    for (int r = 0; r < 16; ++r) {
      if (!(((r >> cb) & 1) && !((r >> tb) & 1))) continue;
      const int r1 = r | (1 << tb);
      h2 t = V[r]; V[r] = V[r1]; V[r1] = t;
    }
  }
}

__device__ __forceinline__ void cascade16(h2 (&V)[16], int lane) {
  const int addr = ((lane ^ (lane >> 1)) << 2);
#pragma unroll
  for (int r = 0; r < 16; ++r)
    V[r] = u2h((unsigned int)__builtin_amdgcn_ds_bpermute(addr, (int)h2u(V[r])));
  apply_cnot16<5>(V, lane);
  apply_cnot16<6>(V, lane);
  apply_cnot16<7>(V, lane);
  apply_cnot16<8>(V, lane);
}

// Batch-uniform RA-layer trig table: tab[0..59] = cos(qp*0.5), tab[60..119] = sin.
__global__ void dqc_trig_kernel(const float* __restrict__ qp, float* __restrict__ tab) {
  int t = threadIdx.x;
  if (t < 60) {
    float th = qp[t] * 0.5f;
    tab[t]      = __cosf(th);
    tab[60 + t] = __sinf(th);
  }
}

__global__ __launch_bounds__(256) void dqc_kernel(
    const float* __restrict__ x, const float* __restrict__ pre_w,
    const float* __restrict__ pre_b, const float* __restrict__ q_params,
    const float* __restrict__ post_w, const float* __restrict__ post_b,
    const float* __restrict__ tab, float* __restrict__ out) {
  const int lane = threadIdx.x & 63;
  const int wave = threadIdx.x >> 6;
  const int b = blockIdx.x * 4 + wave;

  // ---------- pre layer: q_in[w] = tanh(x[b] . pre_w[w] + pre_b[w]) * pi/2
  const float* xb = x + (size_t)b * 512 + lane * 8;
  const float4 xv0 = *(const float4*)(xb);
  const float4 xv1 = *(const float4*)(xb + 4);
  float qin[10];
#pragma unroll
  for (int q = 0; q < 10; ++q) {
    const float* wp = pre_w + q * 512 + lane * 8;
    const float4 w0 = *(const float4*)(wp);
    const float4 w1 = *(const float4*)(wp + 4);
    float a = xv0.x * w0.x + xv0.y * w0.y + xv0.z * w0.z + xv0.w * w0.w +
              xv1.x * w1.x + xv1.y * w1.y + xv1.z * w1.z + xv1.w * w1.w;
    a = bfly_sum(a);
    qin[q] = ftanh(a + pre_b[q]) * (PI_F * 0.5f);
  }

  // angle constants (all wave-uniform)
  float tq[10], phi[9];
#pragma unroll
  for (int w = 0; w < 10; ++w) tq[w] = 2.0f * qin[w];
#pragma unroll
  for (int i = 0; i < 9; ++i)
    phi[i] = 2.0f * (PI_F - qin[i]) * (PI_F - qin[i + 1]);

  float sr[16], si[16];

  // ---------- ZZFM rep 1 (analytic, f32): amp(y) = e^{i*theta1(y)}
  {
    float A1 = 0.0f;
    int bprev = 0;
#pragma unroll
    for (int w = 0; w <= 5; ++w) {
      int bw = (lane >> (5 - w)) & 1;
      A1 += (bw ^ bprev) ? tq[w] : 0.0f;
      bprev = bw;
    }
#pragma unroll
    for (int i = 0; i <= 4; ++i)
      A1 += ((lane >> (5 - (i + 1))) & 1) ? phi[i] : 0.0f;
    const int b5 = lane & 1;
    const float m0 = A1 + (b5 ? tq[6] : 0.0f);   // regs with bit6 = 0
    const float m1 = A1 + (b5 ? 0.0f : tq[6]);   // regs with bit6 = 1
#pragma unroll
    for (int r = 0; r < 16; ++r) {
      const int c6 = (r >> 3) & 1, c7 = (r >> 2) & 1, c8 = (r >> 1) & 1, c9 = r & 1;
      float S = ((c6 ^ c7) ? tq[7] : 0.0f) + ((c7 ^ c8) ? tq[8] : 0.0f) +
                ((c8 ^ c9) ? tq[9] : 0.0f) +
                (c6 ? phi[5] : 0.0f) + (c7 ? phi[6] : 0.0f) +
                (c8 ? phi[7] : 0.0f) + (c9 ? phi[8] : 0.0f);
      float th = (c6 ? m1 : m0) + S;
      sr[r] = __cosf(th);
      si[r] = __sinf(th);
    }
  }

  // ---------- ZZFM rep 2 (f32): H layer (raw), folded diagonal
  apply_h32<0>(sr, si, lane); apply_h32<6>(sr, si, lane);
  apply_h32<1>(sr, si, lane); apply_h32<7>(sr, si, lane);
  apply_h32<3>(sr, si, lane); apply_h32<8>(sr, si, lane);
  apply_h32<2>(sr, si, lane); apply_h32<9>(sr, si, lane);
  apply_h32<4>(sr, si, lane); apply_h32<5>(sr, si, lane);
  {
    float A2 = 0.0f;
    int pfx = 0;
#pragma unroll
    for (int w = 0; w <= 5; ++w) {
      int bw = (lane >> (5 - w)) & 1;
      A2 += bw ? tq[w] : 0.0f;
      pfx ^= bw;
      if (w >= 1) A2 += pfx ? phi[w - 1] : 0.0f;   // phi_{w-1} * p_w
    }
    const bool Lb = pfx;                           // lane parity
#pragma unroll
    for (int r = 0; r < 16; ++r) {
      const int c6 = (r >> 3) & 1, c7 = (r >> 2) & 1, c8 = (r >> 1) & 1, c9 = r & 1;
      const int q6 = c6, q7 = q6 ^ c7, q8 = q7 ^ c8, q9 = q8 ^ c9;
      float S2 = (c6 ? tq[6] : 0.0f) + (c7 ? tq[7] : 0.0f) +
                 (c8 ? tq[8] : 0.0f) + (c9 ? tq[9] : 0.0f);
      float Vv = (q6 ? phi[5] : 0.0f) + (q7 ? phi[6] : 0.0f) +
                 (q8 ? phi[7] : 0.0f) + (q9 ? phi[8] : 0.0f);
      float U = (q6 ? 0.0f : phi[5]) + (q7 ? 0.0f : phi[6]) +
                (q8 ? 0.0f : phi[7]) + (q9 ? 0.0f : phi[8]);
      float th = A2 + (Lb ? (S2 + U) : (S2 + Vv));
      float c = __cosf(th), s = __sinf(th);
      float re = sr[r], im = si[r];
      sr[r] = re * c - im * s;
      si[r] = re * s + im * c;
    }
  }

  // ---------- pack to f16 state: V[r] = (re, im)
  h2 V[16];
#pragma unroll
  for (int r = 0; r < 16; ++r) {
    h2 v; v.x = (_Float16)sr[r]; v.y = (_Float16)si[r];
    V[r] = v;
  }
  cascade16(V, lane);

  // ---------- RealAmplitudes (f16): 6 x (RY layer + CNOT cascade)
#pragma unroll 1
  for (int l = 0; l < 6; ++l) {
    h2 qc[10], qs[10], qsn[10];
    if (tab) {
#pragma unroll
      for (int w = 0; w < 10; ++w) {
        float c = tab[l * 10 + w], s = tab[60 + l * 10 + w];
        qc[w] = hsplat(c); qs[w] = hsplat(s); qsn[w] = hsplat(-s);
      }
    } else {
#pragma unroll
      for (int w = 0; w < 10; ++w) {
        float th = q_params[l * 10 + w] * 0.5f;
        float c = __cosf(th), s = __sinf(th);
        qc[w] = hsplat(c); qs[w] = hsplat(s); qsn[w] = hsplat(-s);
      }
    }
#define RYW(W) apply_ry16<W>(V, lane, qc[W], qs[W], qsn[W]);
    RYW(0) RYW(6) RYW(1) RYW(7) RYW(3) RYW(8) RYW(2) RYW(9) RYW(4) RYW(5)
#undef RYW
    cascade16(V, lane);
  }

  // ---------- epilogue (f32): out = (sum_r p_r * (G(lane) + K[r])), * 2^-20
  const float SC = 1.0f / 1048576.0f;
  const float pw06 = post_w[6], pw07 = post_w[7], pw08 = post_w[8], pw09 = post_w[9];
  const float pw16 = post_w[16], pw17 = post_w[17], pw18 = post_w[18], pw19 = post_w[19];
  float k89a[4], k89b[4];
  {
    float a0 = pw08 + pw09, a1 = pw08 - pw09;
    k89a[0] = a0; k89a[1] = a1; k89a[2] = -a1; k89a[3] = -a0;
    float b0 = pw18 + pw19, b1 = pw18 - pw19;
    k89b[0] = b0; k89b[1] = b1; k89b[2] = -b1; k89b[3] = -b0;
  }
  float G0 = 0.0f, G1 = 0.0f;
#pragma unroll
  for (int w = 0; w < 6; ++w) {
    const bool n = (lane >> (5 - w)) & 1;
    const float pa = post_w[w], pb = post_w[10 + w];
    G0 += n ? -pa : pa;
    G1 += n ? -pb : pb;
  }
  float o0 = 0.0f, o1 = 0.0f;
#pragma unroll
  for (int r = 0; r < 16; ++r) {
    const float K0 = ((r & 8) ? -pw06 : pw06) + ((r & 4) ? -pw07 : pw07) + k89a[r & 3];
    const float K1 = ((r & 8) ? -pw16 : pw16) + ((r & 4) ? -pw17 : pw17) + k89b[r & 3];
    float re = (float)V[r].x, im = (float)V[r].y;
    float p = fmaf(re, re, im * im);
    o0 = fmaf(p, G0 + K0, o0);
    o1 = fmaf(p, G1 + K1, o1);
  }
  o0 = bfly_sum(o0);
  o1 = bfly_sum(o1);

  if (lane == 0) {
    *(float2*)(out + (size_t)b * 2) =
        make_float2(o0 * SC + post_b[0], o1 * SC + post_b[1]);
  }
}

extern "C" void kernel_launch(void* const* d_in, const int* in_sizes, int n_in,
                              void* d_out, int out_size, void* d_ws, size_t ws_size,
                              hipStream_t stream) {
  (void)n_in; (void)out_size;
  const float* x      = (const float*)d_in[0];
  const float* pre_w  = (const float*)d_in[1];
  const float* pre_b  = (const float*)d_in[2];
  const float* qp     = (const float*)d_in[3];
  const float* post_w = (const float*)d_in[4];
  const float* post_b = (const float*)d_in[5];
  float* out = (float*)d_out;

  float* tab = nullptr;
  if (ws_size >= 120 * sizeof(float)) {
    tab = (float*)d_ws;
    hipLaunchKernelGGL(dqc_trig_kernel, dim3(1), dim3(64), 0, stream, qp, tab);
  }

  const int batch = in_sizes[0] / 512;  // 16384
  dim3 grid(batch / 4), block(256);
  hipLaunchKernelGGL(dqc_kernel, grid, block, 0, stream,
                     x, pre_w, pre_b, qp, post_w, post_b, tab, out);
}

// Round 11
// 127.657 us; speedup vs baseline: 1.7779x; 1.0329x over previous
//
#include <hip/hip_runtime.h>
#include <math.h>

#define PI_F 3.14159265358979323846f

typedef _Float16 h2 __attribute__((ext_vector_type(2)));

// One wave = one batch element's 10-qubit statevector.
// Amp index bits[9:4]=lane, bits[3:0]=reg. Wire w <-> bit (9-w).
// Hybrid precision: pre-layer, ZZFM rep1 (analytic phases), rep2 H layer and
// folded diagonal in f32; 6 RA layers + 7 cascades on PACKED f16 state
// V[r]=(re,im), gate math forced to v_pk_{mul,fma}_f16 via inline asm
// (R10 counter arithmetic: ~9.2K VALU/wave vs ~4.3K hand count -> compiler
// likely scalarizes h2 ops; VOP3P f16 is true 2-wide full-rate on CDNA).
// RA trig table prebuilt in ws as packed h2 words: (c,c),(s,s),(-s,-s).
// Shuffles: xor1/2 DPP quad_perm, xor8 DPP row_ror:8, xor4/16 ds_swizzle,
// xor32 shfl. Cascade lane-part = Gray ds_bpermute. H raw; 2^-20 in epilogue.

template <int CTRL>
__device__ __forceinline__ int dppi(int v) {
  return __builtin_amdgcn_update_dpp(v, v, CTRL, 0xF, 0xF, false);
}

template <int M>
__device__ __forceinline__ int shxi(int v) {
  if constexpr (M == 1) {
    return dppi<0xB1>(v);                     // quad_perm [1,0,3,2]
  } else if constexpr (M == 2) {
    return dppi<0x4E>(v);                     // quad_perm [2,3,0,1]
  } else if constexpr (M == 8) {
    return dppi<0x128>(v);                    // row_ror:8 == xor 8
  } else if constexpr (M < 32) {              // 4, 16
    return __builtin_amdgcn_ds_swizzle(v, (M << 10) | 0x1f);
  } else {
    return __shfl_xor(v, 32, 64);
  }
}

template <int M>
__device__ __forceinline__ float shx(float v) {
  return __int_as_float(shxi<M>(__float_as_int(v)));
}

__device__ __forceinline__ float bfly_sum(float v) {
  v += shx<1>(v); v += shx<2>(v); v += shx<4>(v);
  v += shx<8>(v); v += shx<16>(v); v += shx<32>(v);
  return v;
}

__device__ __forceinline__ float ftanh(float x) {
  float e = __expf(2.0f * x);
  return 1.0f - 2.0f / (e + 1.0f);
}

__device__ __forceinline__ unsigned int h2u(h2 v) {
  return __builtin_bit_cast(unsigned int, v);
}
__device__ __forceinline__ h2 u2h(unsigned int v) {
  return __builtin_bit_cast(h2, v);
}
__device__ __forceinline__ h2 hsplat(float f) {
  _Float16 h = (_Float16)f;
  h2 r; r.x = h; r.y = h;
  return r;
}

// TRUE packed f16 math (VOP3P). R6 proved pk asm correctness; f16 pk is
// full-rate 2-wide (unlike pk_f32).
__device__ __forceinline__ h2 pk_fma16(h2 a, h2 b, h2 c) {
  h2 d;
  asm("v_pk_fma_f16 %0, %1, %2, %3" : "=v"(d) : "v"(a), "v"(b), "v"(c));
  return d;
}
__device__ __forceinline__ h2 pk_mul16(h2 a, h2 b) {
  h2 d;
  asm("v_pk_mul_f16 %0, %1, %2" : "=v"(d) : "v"(a), "v"(b));
  return d;
}

// ---------------- f32 gates (rep2 H layer only) ----------------
template <int W>
__device__ __forceinline__ void apply_h32(float (&sr)[16], float (&si)[16], int lane) {
  if constexpr (W <= 5) {
    constexpr int lb = 5 - W;
    const float g = ((lane >> lb) & 1) ? -1.0f : 1.0f;
#pragma unroll
    for (int r = 0; r < 16; ++r) {
      float pr = shx<(1 << lb)>(sr[r]);
      float pi = shx<(1 << lb)>(si[r]);
      sr[r] = fmaf(g, sr[r], pr);
      si[r] = fmaf(g, si[r], pi);
    }
  } else {
    constexpr int rb = 9 - W;
#pragma unroll
    for (int r = 0; r < 16; ++r) {
      if ((r >> rb) & 1) continue;
      const int r1 = r | (1 << rb);
      float a0r = sr[r], a1r = sr[r1], a0i = si[r], a1i = si[r1];
      sr[r]  = a0r + a1r;  si[r]  = a0i + a1i;
      sr[r1] = a0r - a1r;  si[r1] = a0i - a1i;
    }
  }
}

// ---------------- f16 gates (RA layers + cascades) ----------------
template <int W>
__device__ __forceinline__ void apply_ry16(h2 (&V)[16], int lane,
                                           h2 cc, h2 ss, h2 ssn) {
  if constexpr (W <= 5) {
    constexpr int lb = 5 - W;
    const h2 tt = ((lane >> lb) & 1) ? ss : ssn;
#pragma unroll
    for (int r = 0; r < 16; ++r) {
      h2 P = u2h(shxi<(1 << lb)>((int)h2u(V[r])));
      V[r] = pk_fma16(tt, P, pk_mul16(cc, V[r]));
    }
  } else {
    constexpr int rb = 9 - W;
#pragma unroll
    for (int r = 0; r < 16; ++r) {
      if ((r >> rb) & 1) continue;
      const int r1 = r | (1 << rb);
      h2 a = V[r], b = V[r1];
      V[r]  = pk_fma16(ssn, b, pk_mul16(cc, a));   // c*a - s*b
      V[r1] = pk_fma16(ss,  a, pk_mul16(cc, b));   // s*a + c*b
    }
  }
}

template <int C>
__device__ __forceinline__ void apply_cnot16(h2 (&V)[16], int lane) {
  if constexpr (C == 5) {                     // control lane bit 0, target reg bit 3
    const bool ctrl = lane & 1;
#pragma unroll
    for (int r = 0; r < 8; ++r) {
      h2 t0 = V[r], t1 = V[r + 8];
      V[r]     = ctrl ? t1 : t0;
      V[r + 8] = ctrl ? t0 : t1;
    }
  } else {                                    // both reg bits: pure SSA renaming
    constexpr int cb = 9 - C;
    constexpr int tb = 8 - C;
#pragma unroll
    for (int r = 0; r < 16; ++r) {
      if (!(((r >> cb) & 1) && !((r >> tb) & 1))) continue;
      const int r1 = r | (1 << tb);
      h2 t = V[r]; V[r] = V[r1]; V[r1] = t;
    }
  }
}

__device__ __forceinline__ void cascade16(h2 (&V)[16], int lane) {
  const int addr = ((lane ^ (lane >> 1)) << 2);
#pragma unroll
  for (int r = 0; r < 16; ++r)
    V[r] = u2h((unsigned int)__builtin_amdgcn_ds_bpermute(addr, (int)h2u(V[r])));
  apply_cnot16<5>(V, lane);
  apply_cnot16<6>(V, lane);
  apply_cnot16<7>(V, lane);
  apply_cnot16<8>(V, lane);
}

// Batch-uniform RA trig table, packed h2: trig[0..59]=(c,c),
// trig[60..119]=(s,s), trig[120..179]=(-s,-s), index l*10+w.
__global__ void dqc_trig_kernel(const float* __restrict__ qp,
                                unsigned int* __restrict__ trig) {
  int t = threadIdx.x;
  if (t < 60) {
    float th = qp[t] * 0.5f;
    float c = __cosf(th), s = __sinf(th);
    trig[t]       = h2u(hsplat(c));
    trig[60 + t]  = h2u(hsplat(s));
    trig[120 + t] = h2u(hsplat(-s));
  }
}

__global__ __launch_bounds__(256) void dqc_kernel(
    const float* __restrict__ x, const float* __restrict__ pre_w,
    const float* __restrict__ pre_b, const float* __restrict__ q_params,
    const float* __restrict__ post_w, const float* __restrict__ post_b,
    const unsigned int* __restrict__ trig, float* __restrict__ out) {
  const int lane = threadIdx.x & 63;
  const int wave = threadIdx.x >> 6;
  const int b = blockIdx.x * 4 + wave;

  // ---------- pre layer: q_in[w] = tanh(x[b] . pre_w[w] + pre_b[w]) * pi/2
  const float* xb = x + (size_t)b * 512 + lane * 8;
  const float4 xv0 = *(const float4*)(xb);
  const float4 xv1 = *(const float4*)(xb + 4);
  float qin[10];
#pragma unroll
  for (int q = 0; q < 10; ++q) {
    const float* wp = pre_w + q * 512 + lane * 8;
    const float4 w0 = *(const float4*)(wp);
    const float4 w1 = *(const float4*)(wp + 4);
    float a = xv0.x * w0.x + xv0.y * w0.y + xv0.z * w0.z + xv0.w * w0.w +
              xv1.x * w1.x + xv1.y * w1.y + xv1.z * w1.z + xv1.w * w1.w;
    a = bfly_sum(a);
    qin[q] = ftanh(a + pre_b[q]) * (PI_F * 0.5f);
  }

  // angle constants (all wave-uniform)
  float tq[10], phi[9];
#pragma unroll
  for (int w = 0; w < 10; ++w) tq[w] = 2.0f * qin[w];
#pragma unroll
  for (int i = 0; i < 9; ++i)
    phi[i] = 2.0f * (PI_F - qin[i]) * (PI_F - qin[i + 1]);

  float sr[16], si[16];

  // ---------- ZZFM rep 1 (analytic, f32): amp(y) = e^{i*theta1(y)}
  {
    float A1 = 0.0f;
    int bprev = 0;
#pragma unroll
    for (int w = 0; w <= 5; ++w) {
      int bw = (lane >> (5 - w)) & 1;
      A1 += (bw ^ bprev) ? tq[w] : 0.0f;
      bprev = bw;
    }
#pragma unroll
    for (int i = 0; i <= 4; ++i)
      A1 += ((lane >> (5 - (i + 1))) & 1) ? phi[i] : 0.0f;
    const int b5 = lane & 1;
    const float m0 = A1 + (b5 ? tq[6] : 0.0f);   // regs with bit6 = 0
    const float m1 = A1 + (b5 ? 0.0f : tq[6]);   // regs with bit6 = 1
#pragma unroll
    for (int r = 0; r < 16; ++r) {
      const int c6 = (r >> 3) & 1, c7 = (r >> 2) & 1, c8 = (r >> 1) & 1, c9 = r & 1;
      float S = ((c6 ^ c7) ? tq[7] : 0.0f) + ((c7 ^ c8) ? tq[8] : 0.0f) +
                ((c8 ^ c9) ? tq[9] : 0.0f) +
                (c6 ? phi[5] : 0.0f) + (c7 ? phi[6] : 0.0f) +
                (c8 ? phi[7] : 0.0f) + (c9 ? phi[8] : 0.0f);
      float th = (c6 ? m1 : m0) + S;
      sr[r] = __cosf(th);
      si[r] = __sinf(th);
    }
  }

  // ---------- ZZFM rep 2 (f32): H layer (raw), folded diagonal
  apply_h32<0>(sr, si, lane); apply_h32<6>(sr, si, lane);
  apply_h32<1>(sr, si, lane); apply_h32<7>(sr, si, lane);
  apply_h32<3>(sr, si, lane); apply_h32<8>(sr, si, lane);
  apply_h32<2>(sr, si, lane); apply_h32<9>(sr, si, lane);
  apply_h32<4>(sr, si, lane); apply_h32<5>(sr, si, lane);
  {
    float A2 = 0.0f;
    int pfx = 0;
#pragma unroll
    for (int w = 0; w <= 5; ++w) {
      int bw = (lane >> (5 - w)) & 1;
      A2 += bw ? tq[w] : 0.0f;
      pfx ^= bw;
      if (w >= 1) A2 += pfx ? phi[w - 1] : 0.0f;   // phi_{w-1} * p_w
    }
    const bool Lb = pfx;                           // lane parity
#pragma unroll
    for (int r = 0; r < 16; ++r) {
      const int c6 = (r >> 3) & 1, c7 = (r >> 2) & 1, c8 = (r >> 1) & 1, c9 = r & 1;
      const int q6 = c6, q7 = q6 ^ c7, q8 = q7 ^ c8, q9 = q8 ^ c9;
      float S2 = (c6 ? tq[6] : 0.0f) + (c7 ? tq[7] : 0.0f) +
                 (c8 ? tq[8] : 0.0f) + (c9 ? tq[9] : 0.0f);
      float Vv = (q6 ? phi[5] : 0.0f) + (q7 ? phi[6] : 0.0f) +
                 (q8 ? phi[7] : 0.0f) + (q9 ? phi[8] : 0.0f);
      float U = (q6 ? 0.0f : phi[5]) + (q7 ? 0.0f : phi[6]) +
                (q8 ? 0.0f : phi[7]) + (q9 ? 0.0f : phi[8]);
      float th = A2 + (Lb ? (S2 + U) : (S2 + Vv));
      float c = __cosf(th), s = __sinf(th);
      float re = sr[r], im = si[r];
      sr[r] = re * c - im * s;
      si[r] = re * s + im * c;
    }
  }

  // ---------- pack to f16 state: V[r] = (re, im)
  h2 V[16];
#pragma unroll
  for (int r = 0; r < 16; ++r) {
    h2 v; v.x = (_Float16)sr[r]; v.y = (_Float16)si[r];
    V[r] = v;
  }
  cascade16(V, lane);

  // ---------- RealAmplitudes (f16): 6 x (RY layer + CNOT cascade)
#pragma unroll 1
  for (int l = 0; l < 6; ++l) {
    h2 qc[10], qs[10], qsn[10];
    if (trig) {
#pragma unroll
      for (int w = 0; w < 10; ++w) {
        qc[w]  = u2h(trig[l * 10 + w]);
        qs[w]  = u2h(trig[60 + l * 10 + w]);
        qsn[w] = u2h(trig[120 + l * 10 + w]);
      }
    } else {
#pragma unroll
      for (int w = 0; w < 10; ++w) {
        float th = q_params[l * 10 + w] * 0.5f;
        float c = __cosf(th), s = __sinf(th);
        qc[w] = hsplat(c); qs[w] = hsplat(s); qsn[w] = hsplat(-s);
      }
    }
#define RYW(W) apply_ry16<W>(V, lane, qc[W], qs[W], qsn[W]);
    RYW(0) RYW(6) RYW(1) RYW(7) RYW(3) RYW(8) RYW(2) RYW(9) RYW(4) RYW(5)
#undef RYW
    cascade16(V, lane);
  }

  // ---------- epilogue (f32): out = (sum_r p_r * (G(lane) + K[r])), * 2^-20
  const float SC = 1.0f / 1048576.0f;
  const float pw06 = post_w[6], pw07 = post_w[7], pw08 = post_w[8], pw09 = post_w[9];
  const float pw16 = post_w[16], pw17 = post_w[17], pw18 = post_w[18], pw19 = post_w[19];
  float k89a[4], k89b[4];
  {
    float a0 = pw08 + pw09, a1 = pw08 - pw09;
    k89a[0] = a0; k89a[1] = a1; k89a[2] = -a1; k89a[3] = -a0;
    float b0 = pw18 + pw19, b1 = pw18 - pw19;
    k89b[0] = b0; k89b[1] = b1; k89b[2] = -b1; k89b[3] = -b0;
  }
  float G0 = 0.0f, G1 = 0.0f;
#pragma unroll
  for (int w = 0; w < 6; ++w) {
    const bool n = (lane >> (5 - w)) & 1;
    const float pa = post_w[w], pb = post_w[10 + w];
    G0 += n ? -pa : pa;
    G1 += n ? -pb : pb;
  }
  float o0 = 0.0f, o1 = 0.0f;
#pragma unroll
  for (int r = 0; r < 16; ++r) {
    const float K0 = ((r & 8) ? -pw06 : pw06) + ((r & 4) ? -pw07 : pw07) + k89a[r & 3];
    const float K1 = ((r & 8) ? -pw16 : pw16) + ((r & 4) ? -pw17 : pw17) + k89b[r & 3];
    float re = (float)V[r].x, im = (float)V[r].y;
    float p = fmaf(re, re, im * im);
    o0 = fmaf(p, G0 + K0, o0);
    o1 = fmaf(p, G1 + K1, o1);
  }
  o0 = bfly_sum(o0);
  o1 = bfly_sum(o1);

  if (lane == 0) {
    *(float2*)(out + (size_t)b * 2) =
        make_float2(o0 * SC + post_b[0], o1 * SC + post_b[1]);
  }
}

extern "C" void kernel_launch(void* const* d_in, const int* in_sizes, int n_in,
                              void* d_out, int out_size, void* d_ws, size_t ws_size,
                              hipStream_t stream) {
  (void)n_in; (void)out_size;
  const float* x      = (const float*)d_in[0];
  const float* pre_w  = (const float*)d_in[1];
  const float* pre_b  = (const float*)d_in[2];
  const float* qp     = (const float*)d_in[3];
  const float* post_w = (const float*)d_in[4];
  const float* post_b = (const float*)d_in[5];
  float* out = (float*)d_out;

  unsigned int* trig = nullptr;
  if (ws_size >= 180 * sizeof(unsigned int)) {
    trig = (unsigned int*)d_ws;
    hipLaunchKernelGGL(dqc_trig_kernel, dim3(1), dim3(64), 0, stream, qp, trig);
  }

  const int batch = in_sizes[0] / 512;  // 16384
  dim3 grid(batch / 4), block(256);
  hipLaunchKernelGGL(dqc_kernel, grid, block, 0, stream,
                     x, pre_w, pre_b, qp, post_w, post_b, trig, out);
}

// Round 13
// 117.503 us; speedup vs baseline: 1.9316x; 1.0864x over previous
//
#include <hip/hip_runtime.h>
#include <math.h>

#define PI_F 3.14159265358979323846f

typedef _Float16 h2 __attribute__((ext_vector_type(2)));

// One wave = one batch element's 10-qubit statevector.
// Amp index bits[9:4]=lane, bits[3:0]=reg. Wire w <-> bit (9-w).
// f32: pre-layer, ZZFM rep1 analytic init (sincos), rep2 diagonal sincos.
// f16 packed (re,im): rep2 H layer, rep2 diagonal apply, 6 RA layers,
// 7 cascades. pk math via asm v_pk_* (R6-proven correct).
// Shuffles: xor1/2 mov_dpp quad_perm, xor8 mov_dpp row_ror:8 (single-op DPP,
// no old-copy), xor4/16 ds_swizzle, xor32/Gray ds_bpermute (addr hoisted).
// H raw (no 1/sqrt2); 2^-20 prob scale removed in f32 epilogue.

#if __has_builtin(__builtin_amdgcn_mov_dpp)
template <int CTRL>
__device__ __forceinline__ int dppi(int v) {
  return __builtin_amdgcn_mov_dpp(v, CTRL, 0xF, 0xF, false);
}
#else
template <int CTRL>
__device__ __forceinline__ int dppi(int v) {
  return __builtin_amdgcn_update_dpp(v, v, CTRL, 0xF, 0xF, false);
}
#endif

template <int M>
__device__ __forceinline__ int shxi(int v) {
  if constexpr (M == 1) {
    return dppi<0xB1>(v);                     // quad_perm [1,0,3,2]
  } else if constexpr (M == 2) {
    return dppi<0x4E>(v);                     // quad_perm [2,3,0,1]
  } else if constexpr (M == 8) {
    return dppi<0x128>(v);                    // row_ror:8 == xor 8
  } else if constexpr (M < 32) {              // 4, 16
    return __builtin_amdgcn_ds_swizzle(v, (M << 10) | 0x1f);
  } else {
    return __shfl_xor(v, 32, 64);
  }
}

template <int M>
__device__ __forceinline__ float shx(float v) {
  return __int_as_float(shxi<M>(__float_as_int(v)));
}

__device__ __forceinline__ float bfly_sum(float v) {
  v += shx<1>(v); v += shx<2>(v); v += shx<4>(v);
  v += shx<8>(v); v += shx<16>(v); v += shx<32>(v);
  return v;
}

__device__ __forceinline__ float ftanh(float x) {
  float e = __expf(2.0f * x);
  return 1.0f - 2.0f / (e + 1.0f);
}

__device__ __forceinline__ unsigned int h2u(h2 v) {
  return __builtin_bit_cast(unsigned int, v);
}
__device__ __forceinline__ h2 u2h(unsigned int v) {
  return __builtin_bit_cast(h2, v);
}
__device__ __forceinline__ h2 hsplat(float f) {
  _Float16 h = (_Float16)f;
  h2 r; r.x = h; r.y = h;
  return r;
}
// cvt_pkrtz returns __fp16x2; bit_cast to our h2 (same layout)
__device__ __forceinline__ h2 pkrtz(float lo, float hi) {
  return __builtin_bit_cast(h2, __builtin_amdgcn_cvt_pkrtz(lo, hi));
}

__device__ __forceinline__ h2 pk_fma16(h2 a, h2 b, h2 c) {
  h2 d;
  asm("v_pk_fma_f16 %0, %1, %2, %3" : "=v"(d) : "v"(a), "v"(b), "v"(c));
  return d;
}
__device__ __forceinline__ h2 pk_mul16(h2 a, h2 b) {
  h2 d;
  asm("v_pk_mul_f16 %0, %1, %2" : "=v"(d) : "v"(a), "v"(b));
  return d;
}
__device__ __forceinline__ h2 pk_add16(h2 a, h2 b) {
  h2 d;
  asm("v_pk_add_f16 %0, %1, %2" : "=v"(d) : "v"(a), "v"(b));
  return d;
}

#define H2_ONE  0x3C003C00u   // ( 1,  1)
#define H2_MONE 0xBC00BC00u   // (-1, -1)

// ---------------- f16 gates ----------------
// RAW Hadamard (no 1/sqrt2)
template <int W>
__device__ __forceinline__ void apply_h16(h2 (&V)[16], int lane) {
  if constexpr (W <= 5) {
    constexpr int lb = 5 - W;
    const h2 gg = u2h(((lane >> lb) & 1) ? H2_MONE : H2_ONE);
#pragma unroll
    for (int r = 0; r < 16; ++r) {
      h2 P = u2h(shxi<(1 << lb)>((int)h2u(V[r])));
      V[r] = pk_fma16(gg, V[r], P);           // P +/- V
    }
  } else {
    constexpr int rb = 9 - W;
    const h2 M1 = u2h(H2_MONE);
#pragma unroll
    for (int r = 0; r < 16; ++r) {
      if ((r >> rb) & 1) continue;
      const int r1 = r | (1 << rb);
      h2 a = V[r], b = V[r1];
      V[r]  = pk_add16(a, b);
      V[r1] = pk_fma16(b, M1, a);             // a - b
    }
  }
}

template <int W>
__device__ __forceinline__ void apply_ry16(h2 (&V)[16], int lane,
                                           h2 cc, h2 ss, h2 ssn) {
  if constexpr (W <= 5) {
    constexpr int lb = 5 - W;
    const h2 tt = ((lane >> lb) & 1) ? ss : ssn;
#pragma unroll
    for (int r = 0; r < 16; ++r) {
      h2 P = u2h(shxi<(1 << lb)>((int)h2u(V[r])));
      V[r] = pk_fma16(tt, P, pk_mul16(cc, V[r]));
    }
  } else {
    constexpr int rb = 9 - W;
#pragma unroll
    for (int r = 0; r < 16; ++r) {
      if ((r >> rb) & 1) continue;
      const int r1 = r | (1 << rb);
      h2 a = V[r], b = V[r1];
      V[r]  = pk_fma16(ssn, b, pk_mul16(cc, a));   // c*a - s*b
      V[r1] = pk_fma16(ss,  a, pk_mul16(cc, b));   // s*a + c*b
    }
  }
}

template <int C>
__device__ __forceinline__ void apply_cnot16(h2 (&V)[16], int lane) {
  if constexpr (C == 5) {                     // control lane bit 0, target reg bit 3
    const bool ctrl = lane & 1;
#pragma unroll
    for (int r = 0; r < 8; ++r) {
      h2 t0 = V[r], t1 = V[r + 8];
      V[r]     = ctrl ? t1 : t0;
      V[r + 8] = ctrl ? t0 : t1;
    }
  } else {                                    // both reg bits: pure SSA renaming
    constexpr int cb = 9 - C;
    constexpr int tb = 8 - C;
#pragma unroll
    for (int r = 0; r < 16; ++r) {
      if (!(((r >> cb) & 1) && !((r >> tb) & 1))) continue;
      const int r1 = r | (1 << tb);
      h2 t = V[r]; V[r] = V[r1]; V[r1] = t;
    }
  }
}

__device__ __forceinline__ void cascade16(h2 (&V)[16], int lane, int addrG) {
#pragma unroll
  for (int r = 0; r < 16; ++r)
    V[r] = u2h((unsigned int)__builtin_amdgcn_ds_bpermute(addrG, (int)h2u(V[r])));
  apply_cnot16<5>(V, lane);
  apply_cnot16<6>(V, lane);
  apply_cnot16<7>(V, lane);
  apply_cnot16<8>(V, lane);
}

// Batch-uniform RA trig table, packed h2: trig[0..59]=(c,c),
// trig[60..119]=(s,s), trig[120..179]=(-s,-s), index l*10+w.
__global__ void dqc_trig_kernel(const float* __restrict__ qp,
                                unsigned int* __restrict__ trig) {
  int t = threadIdx.x;
  if (t < 60) {
    float th = qp[t] * 0.5f;
    float c = __cosf(th), s = __sinf(th);
    trig[t]       = h2u(hsplat(c));
    trig[60 + t]  = h2u(hsplat(s));
    trig[120 + t] = h2u(hsplat(-s));
  }
}

__global__ __launch_bounds__(256) void dqc_kernel(
    const float* __restrict__ x, const float* __restrict__ pre_w,
    const float* __restrict__ pre_b, const float* __restrict__ q_params,
    const float* __restrict__ post_w, const float* __restrict__ post_b,
    const unsigned int* __restrict__ trig, float* __restrict__ out) {
  const int lane = threadIdx.x & 63;
  const int wave = threadIdx.x >> 6;
  const int b = blockIdx.x * 4 + wave;
  const int addrG = ((lane ^ (lane >> 1)) << 2);   // Gray bpermute addr

  // ---------- pre layer: q_in[w] = tanh(x[b] . pre_w[w] + pre_b[w]) * pi/2
  const float* xb = x + (size_t)b * 512 + lane * 8;
  const float4 xv0 = *(const float4*)(xb);
  const float4 xv1 = *(const float4*)(xb + 4);
  float qin[10];
#pragma unroll
  for (int q = 0; q < 10; ++q) {
    const float* wp = pre_w + q * 512 + lane * 8;
    const float4 w0 = *(const float4*)(wp);
    const float4 w1 = *(const float4*)(wp + 4);
    float a = xv0.x * w0.x + xv0.y * w0.y + xv0.z * w0.z + xv0.w * w0.w +
              xv1.x * w1.x + xv1.y * w1.y + xv1.z * w1.z + xv1.w * w1.w;
    a = bfly_sum(a);
    qin[q] = ftanh(a + pre_b[q]) * (PI_F * 0.5f);
  }

  // angle constants (all wave-uniform)
  float tq[10], phi[9];
#pragma unroll
  for (int w = 0; w < 10; ++w) tq[w] = 2.0f * qin[w];
#pragma unroll
  for (int i = 0; i < 9; ++i)
    phi[i] = 2.0f * (PI_F - qin[i]) * (PI_F - qin[i + 1]);

  h2 V[16];

  // ---------- ZZFM rep 1 (analytic, f32 sincos -> packed f16)
  {
    float A1 = 0.0f;
    int bprev = 0;
#pragma unroll
    for (int w = 0; w <= 5; ++w) {
      int bw = (lane >> (5 - w)) & 1;
      A1 += (bw ^ bprev) ? tq[w] : 0.0f;
      bprev = bw;
    }
#pragma unroll
    for (int i = 0; i <= 4; ++i)
      A1 += ((lane >> (5 - (i + 1))) & 1) ? phi[i] : 0.0f;
    const int b5 = lane & 1;
    const float m0 = A1 + (b5 ? tq[6] : 0.0f);   // regs with bit6 = 0
    const float m1 = A1 + (b5 ? 0.0f : tq[6]);   // regs with bit6 = 1
#pragma unroll
    for (int r = 0; r < 16; ++r) {
      const int c6 = (r >> 3) & 1, c7 = (r >> 2) & 1, c8 = (r >> 1) & 1, c9 = r & 1;
      float S = ((c6 ^ c7) ? tq[7] : 0.0f) + ((c7 ^ c8) ? tq[8] : 0.0f) +
                ((c8 ^ c9) ? tq[9] : 0.0f) +
                (c6 ? phi[5] : 0.0f) + (c7 ? phi[6] : 0.0f) +
                (c8 ? phi[7] : 0.0f) + (c9 ? phi[8] : 0.0f);
      float th = (c6 ? m1 : m0) + S;
      V[r] = pkrtz(__cosf(th), __sinf(th));   // (re, im)
    }
  }

  // ---------- ZZFM rep 2: H layer (raw, f16), folded diagonal, cascade
  apply_h16<0>(V, lane); apply_h16<6>(V, lane);
  apply_h16<1>(V, lane); apply_h16<7>(V, lane);
  apply_h16<3>(V, lane); apply_h16<8>(V, lane);
  apply_h16<2>(V, lane); apply_h16<9>(V, lane);
  apply_h16<4>(V, lane); apply_h16<5>(V, lane);
  {
    float A2 = 0.0f;
    int pfx = 0;
#pragma unroll
    for (int w = 0; w <= 5; ++w) {
      int bw = (lane >> (5 - w)) & 1;
      A2 += bw ? tq[w] : 0.0f;
      pfx ^= bw;
      if (w >= 1) A2 += pfx ? phi[w - 1] : 0.0f;   // phi_{w-1} * p_w
    }
    const bool Lb = pfx;                           // lane parity
#pragma unroll
    for (int r = 0; r < 16; ++r) {
      const int c6 = (r >> 3) & 1, c7 = (r >> 2) & 1, c8 = (r >> 1) & 1, c9 = r & 1;
      const int q6 = c6, q7 = q6 ^ c7, q8 = q7 ^ c8, q9 = q8 ^ c9;
      float S2 = (c6 ? tq[6] : 0.0f) + (c7 ? tq[7] : 0.0f) +
                 (c8 ? tq[8] : 0.0f) + (c9 ? tq[9] : 0.0f);
      float Vv = (q6 ? phi[5] : 0.0f) + (q7 ? phi[6] : 0.0f) +
                 (q8 ? phi[7] : 0.0f) + (q9 ? phi[8] : 0.0f);
      float U = (q6 ? 0.0f : phi[5]) + (q7 ? 0.0f : phi[6]) +
                (q8 ? 0.0f : phi[7]) + (q9 ? 0.0f : phi[8]);
      float th = A2 + (Lb ? (S2 + U) : (S2 + Vv));
      // packed complex multiply by (c + i s):
      // t = V*(c,c); u = halfswap(V) = (im,re); V' = u*(-s,s) + t
      h2 w_cs = pkrtz(__cosf(th), __sinf(th));                      // (c, s)
      unsigned int wu = h2u(w_cs);
      h2 CC = u2h(__builtin_amdgcn_perm(wu, wu, 0x01000100));       // (c, c)
      h2 SS = u2h(__builtin_amdgcn_perm(wu, wu, 0x03020302) ^ 0x00008000u); // (-s, s)
      h2 u  = u2h(__builtin_amdgcn_alignbit(h2u(V[r]), h2u(V[r]), 16));     // (im, re)
      V[r] = pk_fma16(u, SS, pk_mul16(V[r], CC));
    }
  }
  cascade16(V, lane, addrG);

  // ---------- RealAmplitudes (f16): 6 x (RY layer + CNOT cascade)
#pragma unroll 1
  for (int l = 0; l < 6; ++l) {
    h2 qc[10], qs[10], qsn[10];
    if (trig) {
#pragma unroll
      for (int w = 0; w < 10; ++w) {
        qc[w]  = u2h(trig[l * 10 + w]);
        qs[w]  = u2h(trig[60 + l * 10 + w]);
        qsn[w] = u2h(trig[120 + l * 10 + w]);
      }
    } else {
#pragma unroll
      for (int w = 0; w < 10; ++w) {
        float th = q_params[l * 10 + w] * 0.5f;
        float c = __cosf(th), s = __sinf(th);
        qc[w] = hsplat(c); qs[w] = hsplat(s); qsn[w] = hsplat(-s);
      }
    }
#define RYW(W) apply_ry16<W>(V, lane, qc[W], qs[W], qsn[W]);
    RYW(0) RYW(6) RYW(1) RYW(7) RYW(3) RYW(8) RYW(2) RYW(9) RYW(4) RYW(5)
#undef RYW
    cascade16(V, lane, addrG);
  }

  // ---------- epilogue (f32): out = (sum_r p_r * (G(lane) + K[r])), * 2^-20
  const float SC = 1.0f / 1048576.0f;
  const float pw06 = post_w[6], pw07 = post_w[7], pw08 = post_w[8], pw09 = post_w[9];
  const float pw16 = post_w[16], pw17 = post_w[17], pw18 = post_w[18], pw19 = post_w[19];
  float k89a[4], k89b[4];
  {
    float a0 = pw08 + pw09, a1 = pw08 - pw09;
    k89a[0] = a0; k89a[1] = a1; k89a[2] = -a1; k89a[3] = -a0;
    float b0 = pw18 + pw19, b1 = pw18 - pw19;
    k89b[0] = b0; k89b[1] = b1; k89b[2] = -b1; k89b[3] = -b0;
  }
  float G0 = 0.0f, G1 = 0.0f;
#pragma unroll
  for (int w = 0; w < 6; ++w) {
    const bool n = (lane >> (5 - w)) & 1;
    const float pa = post_w[w], pb = post_w[10 + w];
    G0 += n ? -pa : pa;
    G1 += n ? -pb : pb;
  }
  float o0 = 0.0f, o1 = 0.0f;
#pragma unroll
  for (int r = 0; r < 16; ++r) {
    const float K0 = ((r & 8) ? -pw06 : pw06) + ((r & 4) ? -pw07 : pw07) + k89a[r & 3];
    const float K1 = ((r & 8) ? -pw16 : pw16) + ((r & 4) ? -pw17 : pw17) + k89b[r & 3];
    float re = (float)V[r].x, im = (float)V[r].y;
    float p = fmaf(re, re, im * im);
    o0 = fmaf(p, G0 + K0, o0);
    o1 = fmaf(p, G1 + K1, o1);
  }
  o0 = bfly_sum(o0);
  o1 = bfly_sum(o1);

  if (lane == 0) {
    *(float2*)(out + (size_t)b * 2) =
        make_float2(o0 * SC + post_b[0], o1 * SC + post_b[1]);
  }
}

extern "C" void kernel_launch(void* const* d_in, const int* in_sizes, int n_in,
                              void* d_out, int out_size, void* d_ws, size_t ws_size,
                              hipStream_t stream) {
  (void)n_in; (void)out_size;
  const float* x      = (const float*)d_in[0];
  const float* pre_w  = (const float*)d_in[1];
  const float* pre_b  = (const float*)d_in[2];
  const float* qp     = (const float*)d_in[3];
  const float* post_w = (const float*)d_in[4];
  const float* post_b = (const float*)d_in[5];
  float* out = (float*)d_out;

  unsigned int* trig = nullptr;
  if (ws_size >= 180 * sizeof(unsigned int)) {
    trig = (unsigned int*)d_ws;
    hipLaunchKernelGGL(dqc_trig_kernel, dim3(1), dim3(64), 0, stream, qp, trig);
  }

  const int batch = in_sizes[0] / 512;  // 16384
  dim3 grid(batch / 4), block(256);
  hipLaunchKernelGGL(dqc_kernel, grid, block, 0, stream,
                     x, pre_w, pre_b, qp, post_w, post_b, trig, out);
}

// Round 14
// 114.575 us; speedup vs baseline: 1.9809x; 1.0256x over previous
//
#include <hip/hip_runtime.h>
#include <math.h>

#define PI_F 3.14159265358979323846f

typedef _Float16 h2 __attribute__((ext_vector_type(2)));

// One wave = one batch element's 10-qubit statevector.
// Amp index bits[9:4]=lane, bits[3:0]=reg. Wire w <-> bit (9-w).
// f32: pre-layer, angle sums, sincos. f16 packed (re,im): everything else.
// Shuffles: xor1/2 mov_dpp quad_perm, xor8 mov_dpp row_ror:8, xor4/16
// ds_swizzle, xor32/Gray ds_bpermute. H raw; 2^-20 removed in f32 epilogue.

#if __has_builtin(__builtin_amdgcn_mov_dpp)
template <int CTRL>
__device__ __forceinline__ int dppi(int v) {
  return __builtin_amdgcn_mov_dpp(v, CTRL, 0xF, 0xF, false);
}
#else
template <int CTRL>
__device__ __forceinline__ int dppi(int v) {
  return __builtin_amdgcn_update_dpp(v, v, CTRL, 0xF, 0xF, false);
}
#endif

template <int M>
__device__ __forceinline__ int shxi(int v) {
  if constexpr (M == 1) {
    return dppi<0xB1>(v);                     // quad_perm [1,0,3,2]
  } else if constexpr (M == 2) {
    return dppi<0x4E>(v);                     // quad_perm [2,3,0,1]
  } else if constexpr (M == 8) {
    return dppi<0x128>(v);                    // row_ror:8 == xor 8
  } else if constexpr (M < 32) {              // 4, 16
    return __builtin_amdgcn_ds_swizzle(v, (M << 10) | 0x1f);
  } else {
    return __shfl_xor(v, 32, 64);
  }
}

template <int M>
__device__ __forceinline__ float shx(float v) {
  return __int_as_float(shxi<M>(__float_as_int(v)));
}

__device__ __forceinline__ float bfly_sum(float v) {
  v += shx<1>(v); v += shx<2>(v); v += shx<4>(v);
  v += shx<8>(v); v += shx<16>(v); v += shx<32>(v);
  return v;
}

__device__ __forceinline__ float ftanh(float x) {
  float e = __expf(2.0f * x);
  return 1.0f - 2.0f / (e + 1.0f);
}

__device__ __forceinline__ unsigned int h2u(h2 v) {
  return __builtin_bit_cast(unsigned int, v);
}
__device__ __forceinline__ h2 u2h(unsigned int v) {
  return __builtin_bit_cast(h2, v);
}
__device__ __forceinline__ h2 hsplat(float f) {
  _Float16 h = (_Float16)f;
  h2 r; r.x = h; r.y = h;
  return r;
}
__device__ __forceinline__ h2 pkrtz(float lo, float hi) {
  return __builtin_bit_cast(h2, __builtin_amdgcn_cvt_pkrtz(lo, hi));
}

__device__ __forceinline__ h2 pk_fma16(h2 a, h2 b, h2 c) {
  h2 d;
  asm("v_pk_fma_f16 %0, %1, %2, %3" : "=v"(d) : "v"(a), "v"(b), "v"(c));
  return d;
}
__device__ __forceinline__ h2 pk_mul16(h2 a, h2 b) {
  h2 d;
  asm("v_pk_mul_f16 %0, %1, %2" : "=v"(d) : "v"(a), "v"(b));
  return d;
}
__device__ __forceinline__ h2 pk_add16(h2 a, h2 b) {
  h2 d;
  asm("v_pk_add_f16 %0, %1, %2" : "=v"(d) : "v"(a), "v"(b));
  return d;
}

// p = re^2 + im^2 + acc in ONE instruction (v_dot2_f32_f16)
__device__ __forceinline__ float fdot2(h2 a, h2 b, float c) {
#if __has_builtin(__builtin_amdgcn_fdot2)
  return __builtin_amdgcn_fdot2(
      __builtin_bit_cast(__fp16 __attribute__((ext_vector_type(2))), a),
      __builtin_bit_cast(__fp16 __attribute__((ext_vector_type(2))), b), c, false);
#else
  return fmaf((float)a.x, (float)b.x, fmaf((float)a.y, (float)b.y, c));
#endif
}

#define H2_ONE  0x3C003C00u   // ( 1,  1)
#define H2_MONE 0xBC00BC00u   // (-1, -1)

// ---------------- f16 gates ----------------
// RAW Hadamard (no 1/sqrt2)
template <int W>
__device__ __forceinline__ void apply_h16(h2 (&V)[16], int lane) {
  if constexpr (W <= 5) {
    constexpr int lb = 5 - W;
    const h2 gg = u2h(((lane >> lb) & 1) ? H2_MONE : H2_ONE);
#pragma unroll
    for (int r = 0; r < 16; ++r) {
      h2 P = u2h(shxi<(1 << lb)>((int)h2u(V[r])));
      V[r] = pk_fma16(gg, V[r], P);           // P +/- V
    }
  } else {
    constexpr int rb = 9 - W;
    const h2 M1 = u2h(H2_MONE);
#pragma unroll
    for (int r = 0; r < 16; ++r) {
      if ((r >> rb) & 1) continue;
      const int r1 = r | (1 << rb);
      h2 a = V[r], b = V[r1];
      V[r]  = pk_add16(a, b);
      V[r1] = pk_fma16(b, M1, a);             // a - b
    }
  }
}

template <int W>
__device__ __forceinline__ void apply_ry16(h2 (&V)[16], int lane,
                                           h2 cc, h2 ss, h2 ssn) {
  if constexpr (W <= 5) {
    constexpr int lb = 5 - W;
    const h2 tt = ((lane >> lb) & 1) ? ss : ssn;
#pragma unroll
    for (int r = 0; r < 16; ++r) {
      h2 P = u2h(shxi<(1 << lb)>((int)h2u(V[r])));
      V[r] = pk_fma16(tt, P, pk_mul16(cc, V[r]));
    }
  } else {
    constexpr int rb = 9 - W;
#pragma unroll
    for (int r = 0; r < 16; ++r) {
      if ((r >> rb) & 1) continue;
      const int r1 = r | (1 << rb);
      h2 a = V[r], b = V[r1];
      V[r]  = pk_fma16(ssn, b, pk_mul16(cc, a));   // c*a - s*b
      V[r1] = pk_fma16(ss,  a, pk_mul16(cc, b));   // s*a + c*b
    }
  }
}

template <int C>
__device__ __forceinline__ void apply_cnot16(h2 (&V)[16], int lane) {
  if constexpr (C == 5) {                     // control lane bit 0, target reg bit 3
    const bool ctrl = lane & 1;
#pragma unroll
    for (int r = 0; r < 8; ++r) {
      h2 t0 = V[r], t1 = V[r + 8];
      V[r]     = ctrl ? t1 : t0;
      V[r + 8] = ctrl ? t0 : t1;
    }
  } else {                                    // both reg bits: pure SSA renaming
    constexpr int cb = 9 - C;
    constexpr int tb = 8 - C;
#pragma unroll
    for (int r = 0; r < 16; ++r) {
      if (!(((r >> cb) & 1) && !((r >> tb) & 1))) continue;
      const int r1 = r | (1 << tb);
      h2 t = V[r]; V[r] = V[r1]; V[r1] = t;
    }
  }
}

__device__ __forceinline__ void cascade16(h2 (&V)[16], int lane, int addrG) {
#pragma unroll
  for (int r = 0; r < 16; ++r)
    V[r] = u2h((unsigned int)__builtin_amdgcn_ds_bpermute(addrG, (int)h2u(V[r])));
  apply_cnot16<5>(V, lane);
  apply_cnot16<6>(V, lane);
  apply_cnot16<7>(V, lane);
  apply_cnot16<8>(V, lane);
}

// Batch-uniform RA trig table, packed h2: trig[0..59]=(c,c),
// trig[60..119]=(s,s), trig[120..179]=(-s,-s), index l*10+w.
__global__ void dqc_trig_kernel(const float* __restrict__ qp,
                                unsigned int* __restrict__ trig) {
  int t = threadIdx.x;
  if (t < 60) {
    float th = qp[t] * 0.5f;
    float c = __cosf(th), s = __sinf(th);
    trig[t]       = h2u(hsplat(c));
    trig[60 + t]  = h2u(hsplat(s));
    trig[120 + t] = h2u(hsplat(-s));
  }
}

__global__ __launch_bounds__(256) void dqc_kernel(
    const float* __restrict__ x, const float* __restrict__ pre_w,
    const float* __restrict__ pre_b, const float* __restrict__ q_params,
    const float* __restrict__ post_w, const float* __restrict__ post_b,
    const unsigned int* __restrict__ trig, float* __restrict__ out) {
  const int lane = threadIdx.x & 63;
  const int wave = threadIdx.x >> 6;
  const int b = blockIdx.x * 4 + wave;
  const int addrG = ((lane ^ (lane >> 1)) << 2);   // Gray bpermute addr

  // ---------- pre layer: q_in[w] = tanh(x[b] . pre_w[w] + pre_b[w]) * pi/2
  const float* xb = x + (size_t)b * 512 + lane * 8;
  const float4 xv0 = *(const float4*)(xb);
  const float4 xv1 = *(const float4*)(xb + 4);
  float qin[10];
#pragma unroll
  for (int q = 0; q < 10; ++q) {
    const float* wp = pre_w + q * 512 + lane * 8;
    const float4 w0 = *(const float4*)(wp);
    const float4 w1 = *(const float4*)(wp + 4);
    float a = xv0.x * w0.x + xv0.y * w0.y + xv0.z * w0.z + xv0.w * w0.w +
              xv1.x * w1.x + xv1.y * w1.y + xv1.z * w1.z + xv1.w * w1.w;
    a = bfly_sum(a);
    qin[q] = ftanh(a + pre_b[q]) * (PI_F * 0.5f);
  }

  // angle constants (all wave-uniform)
  float tq[10], phi[9];
#pragma unroll
  for (int w = 0; w < 10; ++w) tq[w] = 2.0f * qin[w];
#pragma unroll
  for (int i = 0; i < 9; ++i)
    phi[i] = 2.0f * (PI_F - qin[i]) * (PI_F - qin[i + 1]);

  h2 V[16];

  // ---------- ZZFM rep 1 (analytic, f32 sincos -> packed f16)
  {
    float A1 = 0.0f;
    int bprev = 0;
#pragma unroll
    for (int w = 0; w <= 5; ++w) {
      int bw = (lane >> (5 - w)) & 1;
      A1 += (bw ^ bprev) ? tq[w] : 0.0f;
      bprev = bw;
    }
#pragma unroll
    for (int i = 0; i <= 4; ++i)
      A1 += ((lane >> (5 - (i + 1))) & 1) ? phi[i] : 0.0f;
    const int b5 = lane & 1;
    const float m0 = A1 + (b5 ? tq[6] : 0.0f);   // regs with bit6 = 0
    const float m1 = A1 + (b5 ? 0.0f : tq[6]);   // regs with bit6 = 1
#pragma unroll
    for (int r = 0; r < 16; ++r) {
      const int c6 = (r >> 3) & 1, c7 = (r >> 2) & 1, c8 = (r >> 1) & 1, c9 = r & 1;
      float S = ((c6 ^ c7) ? tq[7] : 0.0f) + ((c7 ^ c8) ? tq[8] : 0.0f) +
                ((c8 ^ c9) ? tq[9] : 0.0f) +
                (c6 ? phi[5] : 0.0f) + (c7 ? phi[6] : 0.0f) +
                (c8 ? phi[7] : 0.0f) + (c9 ? phi[8] : 0.0f);
      float th = (c6 ? m1 : m0) + S;
      V[r] = pkrtz(__cosf(th), __sinf(th));   // (re, im)
    }
  }

  // ---------- ZZFM rep 2: H layer (raw, f16), folded diagonal, cascade
  apply_h16<0>(V, lane); apply_h16<6>(V, lane);
  apply_h16<1>(V, lane); apply_h16<7>(V, lane);
  apply_h16<3>(V, lane); apply_h16<8>(V, lane);
  apply_h16<2>(V, lane); apply_h16<9>(V, lane);
  apply_h16<4>(V, lane); apply_h16<5>(V, lane);
  {
    float A2 = 0.0f;
    int pfx = 0;
#pragma unroll
    for (int w = 0; w <= 5; ++w) {
      int bw = (lane >> (5 - w)) & 1;
      A2 += bw ? tq[w] : 0.0f;
      pfx ^= bw;
      if (w >= 1) A2 += pfx ? phi[w - 1] : 0.0f;   // phi_{w-1} * p_w
    }
    const bool Lb = pfx;                           // lane parity
#pragma unroll
    for (int r = 0; r < 16; ++r) {
      const int c6 = (r >> 3) & 1, c7 = (r >> 2) & 1, c8 = (r >> 1) & 1, c9 = r & 1;
      const int q6 = c6, q7 = q6 ^ c7, q8 = q7 ^ c8, q9 = q8 ^ c9;
      float S2 = (c6 ? tq[6] : 0.0f) + (c7 ? tq[7] : 0.0f) +
                 (c8 ? tq[8] : 0.0f) + (c9 ? tq[9] : 0.0f);
      float Vv = (q6 ? phi[5] : 0.0f) + (q7 ? phi[6] : 0.0f) +
                 (q8 ? phi[7] : 0.0f) + (q9 ? phi[8] : 0.0f);
      float U = (q6 ? 0.0f : phi[5]) + (q7 ? 0.0f : phi[6]) +
                (q8 ? 0.0f : phi[7]) + (q9 ? 0.0f : phi[8]);
      float th = A2 + (Lb ? (S2 + U) : (S2 + Vv));
      // packed complex multiply by (c + i s):
      float c = __cosf(th), s = __sinf(th);
      h2 CC = pkrtz(c, c);                          // (c, c)
      h2 SS = pkrtz(-s, s);                         // (-s, s)
      h2 u  = u2h(__builtin_amdgcn_alignbit(h2u(V[r]), h2u(V[r]), 16)); // (im, re)
      V[r] = pk_fma16(u, SS, pk_mul16(V[r], CC));
    }
  }
  cascade16(V, lane, addrG);

  // ---------- RealAmplitudes (f16): 6 x (RY layer + CNOT cascade)
#pragma unroll
  for (int l = 0; l < 6; ++l) {
    h2 qc[10], qs[10], qsn[10];
    if (trig) {
#pragma unroll
      for (int w = 0; w < 10; ++w) {
        qc[w]  = u2h(trig[l * 10 + w]);
        qs[w]  = u2h(trig[60 + l * 10 + w]);
        qsn[w] = u2h(trig[120 + l * 10 + w]);
      }
    } else {
#pragma unroll
      for (int w = 0; w < 10; ++w) {
        float th = q_params[l * 10 + w] * 0.5f;
        float c = __cosf(th), s = __sinf(th);
        qc[w] = hsplat(c); qs[w] = hsplat(s); qsn[w] = hsplat(-s);
      }
    }
#define RYW(W) apply_ry16<W>(V, lane, qc[W], qs[W], qsn[W]);
    RYW(0) RYW(6) RYW(1) RYW(7) RYW(3) RYW(8) RYW(2) RYW(9) RYW(4) RYW(5)
#undef RYW
    cascade16(V, lane, addrG);
  }

  // ---------- epilogue (f32): out = (sum_r p_r * (G(lane) + K[r])), * 2^-20
  const float SC = 1.0f / 1048576.0f;
  const float pw06 = post_w[6], pw07 = post_w[7], pw08 = post_w[8], pw09 = post_w[9];
  const float pw16 = post_w[16], pw17 = post_w[17], pw18 = post_w[18], pw19 = post_w[19];
  float k89a[4], k89b[4];
  {
    float a0 = pw08 + pw09, a1 = pw08 - pw09;
    k89a[0] = a0; k89a[1] = a1; k89a[2] = -a1; k89a[3] = -a0;
    float b0 = pw18 + pw19, b1 = pw18 - pw19;
    k89b[0] = b0; k89b[1] = b1; k89b[2] = -b1; k89b[3] = -b0;
  }
  float G0 = 0.0f, G1 = 0.0f;
#pragma unroll
  for (int w = 0; w < 6; ++w) {
    const bool n = (lane >> (5 - w)) & 1;
    const float pa = post_w[w], pb = post_w[10 + w];
    G0 += n ? -pa : pa;
    G1 += n ? -pb : pb;
  }
  float o0 = 0.0f, o1 = 0.0f;
#pragma unroll
  for (int r = 0; r < 16; ++r) {
    const float K0 = ((r & 8) ? -pw06 : pw06) + ((r & 4) ? -pw07 : pw07) + k89a[r & 3];
    const float K1 = ((r & 8) ? -pw16 : pw16) + ((r & 4) ? -pw17 : pw17) + k89b[r & 3];
    float p = fdot2(V[r], V[r], 0.0f);        // re^2 + im^2, 1 instr
    o0 = fmaf(p, G0 + K0, o0);
    o1 = fmaf(p, G1 + K1, o1);
  }
  o0 = bfly_sum(o0);
  o1 = bfly_sum(o1);

  if (lane == 0) {
    *(float2*)(out + (size_t)b * 2) =
        make_float2(o0 * SC + post_b[0], o1 * SC + post_b[1]);
  }
}

extern "C" void kernel_launch(void* const* d_in, const int* in_sizes, int n_in,
                              void* d_out, int out_size, void* d_ws, size_t ws_size,
                              hipStream_t stream) {
  (void)n_in; (void)out_size;
  const float* x      = (const float*)d_in[0];
  const float* pre_w  = (const float*)d_in[1];
  const float* pre_b  = (const float*)d_in[2];
  const float* qp     = (const float*)d_in[3];
  const float* post_w = (const float*)d_in[4];
  const float* post_b = (const float*)d_in[5];
  float* out = (float*)d_out;

  unsigned int* trig = nullptr;
  if (ws_size >= 180 * sizeof(unsigned int)) {
    trig = (unsigned int*)d_ws;
    hipLaunchKernelGGL(dqc_trig_kernel, dim3(1), dim3(64), 0, stream, qp, trig);
  }

  const int batch = in_sizes[0] / 512;  // 16384
  dim3 grid(batch / 4), block(256);
  hipLaunchKernelGGL(dqc_kernel, grid, block, 0, stream,
                     x, pre_w, pre_b, qp, post_w, post_b, trig, out);
}